// Round 13
// baseline (417.957 us; speedup 1.0000x reference)
//
#include <hip/hip_runtime.h>
#include <hip/hip_bf16.h>
#include <hip/hip_fp16.h>
#include <math.h>

#define NN 60000
#define NE 200000
#define DD 128
#define NH 4
#define HC 512   // NH * C
#define NL 3
#define VAv 128
#define VBv 16
#define SCAN_CHUNK 512

typedef __attribute__((ext_vector_type(8))) short bf16x8;
typedef __attribute__((ext_vector_type(4))) float f32x4;
typedef _Float16 h2 __attribute__((ext_vector_type(2)));
typedef __fp16 fp16x2 __attribute__((ext_vector_type(2)));

__device__ __forceinline__ float bf2f(unsigned short u){
    union{unsigned int i; float f;} v; v.i = ((unsigned int)u)<<16; return v.f;
}
__device__ __forceinline__ unsigned short f2bf(float f){
    union{float f; unsigned int i;} v; v.f = f;
    unsigned int r = v.i + 0x7fffu + ((v.i>>16)&1u);
    return (unsigned short)(r>>16);
}
__device__ __forceinline__ h2 as_h2(unsigned int u){
    union{unsigned int x; h2 h;} c; c.x = u; return c.h;
}
__device__ __forceinline__ unsigned int pkrtz_u(float a, float b){
    union{fp16x2 h; unsigned int x;} c; c.h = __builtin_amdgcn_cvt_pkrtz(a, b); return c.x;
}

#define GLOAD_LDS16(g, l) \
    __builtin_amdgcn_global_load_lds((const __attribute__((address_space(1))) void*)(g), \
                                     (__attribute__((address_space(3))) void*)(l), 16, 0, 0)

// ---------------- embedding gather: h[n,:] = atom_emb[x[n],:] (fp32 + bf16) ----------
__global__ void k_embed(const int* __restrict__ x, const float* __restrict__ atom_emb,
                        float* __restrict__ h, unsigned short* __restrict__ hb) {
    int idx = blockIdx.x*blockDim.x + threadIdx.x;   // float4 index
    if (idx >= NN*(DD/4)) return;
    int n = idx >> 5;
    int c4 = idx & 31;
    int a = x[n];
    float4 v = ((const float4*)(atom_emb + (size_t)a*DD))[c4];
    ((float4*)(h + (size_t)n*DD))[c4] = v;
    ushort4 u = make_ushort4(f2bf(v.x), f2bf(v.y), f2bf(v.z), f2bf(v.w));
    ((ushort4*)(hb + (size_t)n*DD))[c4] = u;
}

// -------- weight convert: [Wl|Wr] -> Wlrt[l][1024][128] bf16 transposed; blr ---------
__global__ void k_convw(const float* __restrict__ Wl, const float* __restrict__ Wr,
                        const float* __restrict__ bl, const float* __restrict__ br,
                        unsigned short* __restrict__ Wlrt, float* __restrict__ blr) {
    int t = blockIdx.x*256 + threadIdx.x;
    if (t < NL*1024*DD) {
        int l = t / (1024*DD);
        int r = t % (1024*DD);
        int n = r / DD;      // 0..1023
        int k = r % DD;
        float v = (n < HC) ? Wl[(size_t)l*DD*HC + (size_t)k*HC + n]
                           : Wr[(size_t)l*DD*HC + (size_t)k*HC + (n - HC)];
        Wlrt[t] = f2bf(v);
    }
    if (t < NL*1024) {
        int l = t / 1024, j = t % 1024;
        blr[t] = (j < HC) ? bl[(size_t)l*HC + j] : br[(size_t)l*HC + (j - HC)];
    }
}

// ---------------- Wa convert: fp32 [128][128] -> bf16 transposed ---------------------
__global__ void k_convwa(const float* __restrict__ Wa, unsigned short* __restrict__ Wat) {
    int t = blockIdx.x*256 + threadIdx.x;
    if (t >= DD*VAv) return;
    int n = t / DD;
    int k = t % DD;
    Wat[t] = f2bf(Wa[(size_t)k*VAv + n]);
}

// ---------------- Wb convert: fp32 [256][16] -> Wbt bf16 [16][256] -------------------
__global__ void k_convwb(const float* __restrict__ Wb, unsigned short* __restrict__ Wbt) {
    int t = blockIdx.x*256 + threadIdx.x;
    if (t >= 16*256) return;
    int c = t >> 8, k = t & 255;
    Wbt[t] = f2bf(Wb[(size_t)k*16 + c]);
}

// -------- eproj (all layers): f16 linear [l][v][n] -----------------------------------
__global__ void k_eproj(const float* __restrict__ bond_emb, const float* __restrict__ We,
                        __half* __restrict__ eprojh) {
    int t = blockIdx.x*256 + threadIdx.x;    // 24576 total
    if (t >= NL*VBv*HC) return;
    int n = t & (HC-1);
    int v = (t >> 9) & (VBv-1);
    int l = t >> 13;
    const float* be = bond_emb + (size_t)v*DD;         // wave-uniform -> scalar
    const float* w  = We + (size_t)l*DD*HC + n;
    float acc = 0.f;
    #pragma unroll 8
    for (int k = 0; k < DD; ++k) acc = fmaf(be[k], w[(size_t)k*HC], acc);
    eprojh[t] = __float2half(acc);
}

// ---------------- CSR build ----------------
__global__ void k_deg(const int* __restrict__ dst, int* __restrict__ deg) {
    int e = blockIdx.x*blockDim.x + threadIdx.x;
    if (e < NE) atomicAdd(&deg[dst[e]], 1);
}

__global__ void k_scan1(const int* __restrict__ deg, int* __restrict__ exc, int* __restrict__ sums) {
    __shared__ int buf[2][SCAN_CHUNK];
    int t = threadIdx.x;
    int gi = blockIdx.x*SCAN_CHUNK + t;
    int v = (gi < NN) ? deg[gi] : 0;
    buf[0][t] = v;
    __syncthreads();
    int cur = 0;
    for (int off = 1; off < SCAN_CHUNK; off <<= 1) {
        int nv = buf[cur][t] + ((t >= off) ? buf[cur][t-off] : 0);
        buf[cur^1][t] = nv;
        __syncthreads();
        cur ^= 1;
    }
    if (gi < NN) exc[gi] = buf[cur][t] - v;
    if (t == SCAN_CHUNK-1) sums[blockIdx.x] = buf[cur][t];
}

__global__ void k_scan2(int* sums, int nb) {     // nb <= 128
    __shared__ int buf[2][128];
    int t = threadIdx.x;
    int v = (t < nb) ? sums[t] : 0;
    buf[0][t] = v;
    __syncthreads();
    int cur = 0;
    for (int off = 1; off < 128; off <<= 1) {
        int nv = buf[cur][t] + ((t >= off) ? buf[cur][t-off] : 0);
        buf[cur^1][t] = nv;
        __syncthreads();
        cur ^= 1;
    }
    if (t < nb) sums[t] = buf[cur][t] - v;       // exclusive
}

__global__ void k_scan3(const int* __restrict__ exc, const int* __restrict__ sums,
                        int* __restrict__ rowptr) {
    int i = blockIdx.x*blockDim.x + threadIdx.x;
    if (i < NN) rowptr[i] = exc[i] + sums[i / SCAN_CHUNK];
    if (i == NN) rowptr[NN] = NE;
}

// scatter: store src | (eattr<<16) sorted by dst  (src < 65536, eattr < 16)
__global__ void k_scatter(const int* __restrict__ srcv, const int* __restrict__ dst,
                          const int* __restrict__ eattr, const int* __restrict__ rowptr,
                          int* __restrict__ cnt, int* __restrict__ packed) {
    int e = blockIdx.x*blockDim.x + threadIdx.x;
    if (e < NE) {
        int d = dst[e];
        int pos = atomicAdd(&cnt[d], 1);
        packed[rowptr[d] + pos] = srcv[e] | (eattr[e] << 16);
    }
}

// ---------------- MFMA bf16 GEMM: OM=0 fp32 out, OM=2 f16 split planes ----------------
// OM==2: cols 0..511 -> CoutA[row*512+col], cols 512..1023 -> CoutB[row*512+col-512].
template<int OM, int MT, bool SWZ>
__global__ __launch_bounds__(256)
void k_gemm_mfma(const unsigned short* __restrict__ A,
                 const unsigned short* __restrict__ Bt,
                 const float* __restrict__ bias, void* __restrict__ CoutA,
                 void* __restrict__ CoutB,
                 int M, int Nc, int NP) {
    __shared__ unsigned short As[2][128*128];      // 64 KB
    const int tid = threadIdx.x;
    const int lane = tid & 63;
    const int wave = tid >> 6;

    int bn, bm0;
    if (SWZ) {
        int F = blockIdx.x;
        int P = (F & 7) + ((F >> 6) << 3);
        if (P >= NP) return;
        bn  = ((F >> 3) & 7) * 128;
        bm0 = P * (128*MT);
    } else {
        bn  = blockIdx.x * 128;
        bm0 = blockIdx.y * (128*MT);
    }

    const int l15 = lane & 15;
    const int l4  = lane >> 4;
    const int wm = (wave >> 1) * 64;
    const int wn = (wave & 1) * 64;

    // OM==2 plane select (uniform per block: the 128-col n-tile is wholly in one plane)
    unsigned short* oplane = (unsigned short*)((OM == 2 && bn >= 512) ? CoutB : CoutA);
    const int ocolbase = (OM == 2) ? (bn & 511) : bn;
    const int ostride  = (OM == 2) ? 512 : Nc;

    // B fragments once (L2-hot), reused across all MT tiles
    bf16x8 bfr[4][4];
    #pragma unroll
    for (int ks = 0; ks < 4; ++ks)
        #pragma unroll
        for (int ni = 0; ni < 4; ++ni)
            bfr[ks][ni] = *(const bf16x8*)(Bt + (size_t)(bn + wn + ni*16 + l15)*128
                                              + (size_t)(ks*4 + l4)*8);

    float4 bv[4];
    #pragma unroll
    for (int ni = 0; ni < 4; ++ni)
        bv[ni] = bias ? *(const float4*)(bias + bn + wn + ni*16 + l4*4)
                      : make_float4(0.f, 0.f, 0.f, 0.f);

    auto stage = [&](int buf, int bm) {
        #pragma unroll
        for (int it = 0; it < 8; ++it) {
            int slot = it*256 + tid;        // 16B-chunk slot, 2048 per tile
            int row  = slot >> 4;
            int cph  = slot & 15;
            int clog = cph ^ (row & 15);
            int arow = bm + row; if (arow >= M) arow = M - 1;
            unsigned short* ldst = &As[buf][(size_t)(it*256 + (tid & ~63))*8];
            GLOAD_LDS16(A + (size_t)arow*128 + clog*8, ldst);
        }
    };

    stage(0, bm0);
    asm volatile("s_waitcnt vmcnt(0)" ::: "memory");
    __syncthreads();

    int cur = 0;
    for (int t = 0; t < MT; ++t) {
        int bm = bm0 + t*128;
        if (bm >= M) break;
        bool pf = (t+1 < MT) && (bm + 128 < M);
        if (pf) stage(cur^1, bm + 128);            // 8 DMA loads in flight

        f32x4 acc[4][4];
        #pragma unroll
        for (int i = 0; i < 4; ++i)
            #pragma unroll
            for (int j = 0; j < 4; ++j)
                acc[i][j] = (f32x4){0.f, 0.f, 0.f, 0.f};

        #pragma unroll
        for (int ks = 0; ks < 4; ++ks) {
            bf16x8 af[4];
            int cph = (ks*4 + l4) ^ l15;           // row&15 == l15 for fragment rows
            #pragma unroll
            for (int mi = 0; mi < 4; ++mi) {
                int row = wm + mi*16 + l15;
                af[mi] = *(const bf16x8*)(&As[cur][(size_t)row*128 + cph*8]);
            }
            #pragma unroll
            for (int mi = 0; mi < 4; ++mi)
                #pragma unroll
                for (int ni = 0; ni < 4; ++ni)
                    acc[mi][ni] = __builtin_amdgcn_mfma_f32_16x16x32_bf16(bfr[ks][ni], af[mi], acc[mi][ni], 0, 0, 0);
        }

        // epilogue: row = bm+wm+mi*16+l15; cols = bn+wn+ni*16+l4*4 .. +3
        #pragma unroll
        for (int mi = 0; mi < 4; ++mi) {
            int row = bm + wm + mi*16 + l15;
            bool rok = (row < M);
            #pragma unroll
            for (int ni = 0; ni < 4; ++ni) {
                float v0 = acc[mi][ni][0] + bv[ni].x;
                float v1 = acc[mi][ni][1] + bv[ni].y;
                float v2 = acc[mi][ni][2] + bv[ni].z;
                float v3 = acc[mi][ni][3] + bv[ni].w;
                int colb = ocolbase + wn + ni*16 + l4*4;
                if (rok) {
                    if (OM == 2) {
                        *(uint2*)(oplane + (size_t)row*512 + colb)
                            = make_uint2(pkrtz_u(v0, v1), pkrtz_u(v2, v3));
                    } else {
                        *(float4*)((float*)oplane + (size_t)row*ostride + colb) = make_float4(v0, v1, v2, v3);
                    }
                }
            }
        }

        if (pf) {
            asm volatile("s_waitcnt vmcnt(16)" ::: "memory");
            __builtin_amdgcn_s_barrier();          // all waves done reading As[cur]
        }
        cur ^= 1;
    }
}

// ---- fused edge-logits + softmax + aggregate + epilogue (f16, split planes) --------
// 8 waves/block, one node per wave, grid-stride with next-node xr/rowptr prefetch.
// Lane l: channels l*8..+8 (f16). Gathers touch only the xl plane (60 MB).
__global__ __launch_bounds__(512)
void k_aggregate(const unsigned short* __restrict__ xlp,   // [NN][512] f16
                 const unsigned short* __restrict__ xrp,   // [NN][512] f16
                 const __half* __restrict__ eprojh,  // [16][512] f16, this layer
                 const int* __restrict__ rowptr, const int* __restrict__ packed,
                 const float* __restrict__ att,      // [4][128], this layer
                 const float* __restrict__ bias,     // [128], this layer
                 float* __restrict__ h, unsigned short* __restrict__ hb) {
    __shared__ uint4 eps4[1024];                     // 16 KB
    {
        const uint4* s4 = (const uint4*)eprojh;
        int t = threadIdx.x;
        eps4[t]       = s4[t];
        eps4[t + 512] = s4[t + 512];
    }
    __syncthreads();

    const int wave = threadIdx.x >> 6;
    const int lane = threadIdx.x & 63;
    const int loff = lane*8;                         // ushort index into 512-ch row
    const h2 k02 = {(_Float16)0.2f, (_Float16)0.2f};
    const int NG = NN/8;

    h2 attf[4];
    {
        float4 a0 = *(const float4*)(att + loff);
        float4 a1 = *(const float4*)(att + loff + 4);
        attf[0] = (h2){(_Float16)a0.x, (_Float16)a0.y};
        attf[1] = (h2){(_Float16)a0.z, (_Float16)a0.w};
        attf[2] = (h2){(_Float16)a1.x, (_Float16)a1.y};
        attf[3] = (h2){(_Float16)a1.z, (_Float16)a1.w};
    }

#define EDGE_PROC(xr_, er_) do {                                            \
        h2 x0 = as_h2(xr_.x), x1 = as_h2(xr_.y);                            \
        h2 x2 = as_h2(xr_.z), x3 = as_h2(xr_.w);                            \
        h2 z0 = x0 + xrf[0] + as_h2(er_.x);                                 \
        h2 z1 = x1 + xrf[1] + as_h2(er_.y);                                 \
        h2 z2 = x2 + xrf[2] + as_h2(er_.z);                                 \
        h2 z3 = x3 + xrf[3] + as_h2(er_.w);                                 \
        h2 lacc = __builtin_elementwise_max(z0, z0*k02) * attf[0];          \
        lacc += __builtin_elementwise_max(z1, z1*k02) * attf[1];            \
        lacc += __builtin_elementwise_max(z2, z2*k02) * attf[2];            \
        lacc += __builtin_elementwise_max(z3, z3*k02) * attf[3];            \
        float pz_ = (float)lacc[0] + (float)lacc[1];                        \
        pz_ += __shfl_xor(pz_, 1);                                          \
        pz_ += __shfl_xor(pz_, 2);                                          \
        pz_ += __shfl_xor(pz_, 4);                                          \
        pz_ += __shfl_xor(pz_, 8);                                          \
        float w_ = __expf(pz_);                                             \
        wsum += w_;                                                         \
        h2 wh = {(_Float16)w_, (_Float16)w_};                               \
        acc0 += wh*x0; acc1 += wh*x1; acc2 += wh*x2; acc3 += wh*x3;         \
    } while (0)

    int g = blockIdx.x;
    if (g >= NG) return;
    int n = g*8 + wave;
    uint4 xr_raw = *(const uint4*)(xrp + (size_t)n*512 + loff);
    int beg = rowptr[n], end = rowptr[n+1];

    while (true) {
        int gn = g + gridDim.x;
        // prefetch next node's xr + rowptr while processing current
        uint4 xr_next;
        int beg_next = 0, end_next = 0;
        bool more = (gn < NG);
        if (more) {
            int nn2 = gn*8 + wave;
            xr_next = *(const uint4*)(xrp + (size_t)nn2*512 + loff);
            beg_next = rowptr[nn2];
            end_next = rowptr[nn2+1];
        }

        h2 xrf[4];
        xrf[0] = as_h2(xr_raw.x); xrf[1] = as_h2(xr_raw.y);
        xrf[2] = as_h2(xr_raw.z); xrf[3] = as_h2(xr_raw.w);

        h2 acc0 = {0,0}, acc1 = {0,0}, acc2 = {0,0}, acc3 = {0,0};
        float wsum = 0.f;
        int p = beg;

        for (; p + 4 <= end; p += 4) {               // 4 edges in flight
            int pk0 = packed[p],   pk1 = packed[p+1];
            int pk2 = packed[p+2], pk3 = packed[p+3];
            uint4 v0 = *(const uint4*)(xlp + (size_t)(pk0 & 0xFFFF)*512 + loff);
            uint4 v1 = *(const uint4*)(xlp + (size_t)(pk1 & 0xFFFF)*512 + loff);
            uint4 v2 = *(const uint4*)(xlp + (size_t)(pk2 & 0xFFFF)*512 + loff);
            uint4 v3 = *(const uint4*)(xlp + (size_t)(pk3 & 0xFFFF)*512 + loff);
            uint4 e0 = eps4[(pk0 >> 16)*64 + lane];
            uint4 e1 = eps4[(pk1 >> 16)*64 + lane];
            uint4 e2 = eps4[(pk2 >> 16)*64 + lane];
            uint4 e3 = eps4[(pk3 >> 16)*64 + lane];
            EDGE_PROC(v0, e0);
            EDGE_PROC(v1, e1);
            EDGE_PROC(v2, e2);
            EDGE_PROC(v3, e3);
        }
        if (p + 2 <= end) {                          // 2-wide tail
            int pk0 = packed[p], pk1 = packed[p+1];
            uint4 v0 = *(const uint4*)(xlp + (size_t)(pk0 & 0xFFFF)*512 + loff);
            uint4 v1 = *(const uint4*)(xlp + (size_t)(pk1 & 0xFFFF)*512 + loff);
            uint4 e0 = eps4[(pk0 >> 16)*64 + lane];
            uint4 e1 = eps4[(pk1 >> 16)*64 + lane];
            EDGE_PROC(v0, e0);
            EDGE_PROC(v1, e1);
            p += 2;
        }
        if (p < end) {                               // 1-wide tail
            int pk0 = packed[p];
            uint4 v0 = *(const uint4*)(xlp + (size_t)(pk0 & 0xFFFF)*512 + loff);
            uint4 e0 = eps4[(pk0 >> 16)*64 + lane];
            EDGE_PROC(v0, e0);
        }

        float inv = __builtin_amdgcn_rcpf(wsum + 1e-16f);
        float rr[8];
        rr[0] = (float)acc0[0]; rr[1] = (float)acc0[1];
        rr[2] = (float)acc1[0]; rr[3] = (float)acc1[1];
        rr[4] = (float)acc2[0]; rr[5] = (float)acc2[1];
        rr[6] = (float)acc3[0]; rr[7] = (float)acc3[1];
        #pragma unroll
        for (int u = 0; u < 8; ++u) rr[u] *= inv;
        #pragma unroll
        for (int u = 0; u < 8; ++u) rr[u] += __shfl_xor(rr[u], 16);
        #pragma unroll
        for (int u = 0; u < 8; ++u) rr[u] += __shfl_xor(rr[u], 32);

        if (lane < 16) {
            int c = lane*8;
            float* hp = h + (size_t)n*DD + c;
            float4 h0 = *(const float4*)hp;
            float4 h1 = *(const float4*)(hp + 4);
            float4 b0 = *(const float4*)(bias + c);
            float4 b1 = *(const float4*)(bias + c + 4);
            float o[8];
            o[0] = h0.x + fmaxf(0.f, fmaf(0.25f, rr[0], b0.x));
            o[1] = h0.y + fmaxf(0.f, fmaf(0.25f, rr[1], b0.y));
            o[2] = h0.z + fmaxf(0.f, fmaf(0.25f, rr[2], b0.z));
            o[3] = h0.w + fmaxf(0.f, fmaf(0.25f, rr[3], b0.w));
            o[4] = h1.x + fmaxf(0.f, fmaf(0.25f, rr[4], b1.x));
            o[5] = h1.y + fmaxf(0.f, fmaf(0.25f, rr[5], b1.y));
            o[6] = h1.z + fmaxf(0.f, fmaf(0.25f, rr[6], b1.z));
            o[7] = h1.w + fmaxf(0.f, fmaf(0.25f, rr[7], b1.w));
            *(float4*)hp       = make_float4(o[0], o[1], o[2], o[3]);
            *(float4*)(hp + 4) = make_float4(o[4], o[5], o[6], o[7]);
            ushort4 u0 = make_ushort4(f2bf(o[0]), f2bf(o[1]), f2bf(o[2]), f2bf(o[3]));
            ushort4 u1 = make_ushort4(f2bf(o[4]), f2bf(o[5]), f2bf(o[6]), f2bf(o[7]));
            unsigned short* hbp = hb + (size_t)n*DD + c;
            *(ushort4*)hbp       = u0;
            *(ushort4*)(hbp + 4) = u1;
        }

        if (!more) break;
        g = gn; n = gn*8 + wave;
        xr_raw = xr_next; beg = beg_next; end = end_next;
    }
#undef EDGE_PROC
}

// ---------------- bond head v2: MFMA, wave = 16 edges ---------------------------------
__global__ __launch_bounds__(256)
void k_bond(const unsigned short* __restrict__ hb,
            const int* __restrict__ srcv, const int* __restrict__ dstv,
            const unsigned short* __restrict__ Wbt, const float* __restrict__ bb,
            float* __restrict__ out) {
    int lane = threadIdx.x & 63;
    int wave = threadIdx.x >> 6;
    int ebase = blockIdx.x*64 + wave*16;     // NE = 200000 = 3125*64 exact
    int l15 = lane & 15, l4 = lane >> 4;
    int e = ebase + l15;
    const unsigned short* hs = hb + (size_t)srcv[e]*DD;
    const unsigned short* hd = hb + (size_t)dstv[e]*DD;

    bf16x8 bfr[8];
    #pragma unroll
    for (int s = 0; s < 8; ++s)
        bfr[s] = *(const bf16x8*)(Wbt + l15*256 + s*32 + l4*8);

    float bbv = bb[l15];
    f32x4 acc = (f32x4){bbv, bbv, bbv, bbv};
    #pragma unroll
    for (int s = 0; s < 4; ++s) {
        bf16x8 af = *(const bf16x8*)(hs + s*32 + l4*8);
        acc = __builtin_amdgcn_mfma_f32_16x16x32_bf16(af, bfr[s], acc, 0, 0, 0);
    }
    #pragma unroll
    for (int s = 0; s < 4; ++s) {
        bf16x8 af = *(const bf16x8*)(hd + s*32 + l4*8);
        acc = __builtin_amdgcn_mfma_f32_16x16x32_bf16(af, bfr[4+s], acc, 0, 0, 0);
    }
    #pragma unroll
    for (int r = 0; r < 4; ++r)
        out[(size_t)(ebase + l4*4 + r)*16 + l15] = acc[r];
}

// ---------------- host ----------------
extern "C" void kernel_launch(void* const* d_in, const int* in_sizes, int n_in,
                              void* d_out, int out_size, void* d_ws, size_t ws_size,
                              hipStream_t stream) {
    const int*   x        = (const int*)d_in[0];
    const int*   edge_idx = (const int*)d_in[1];
    const int*   eattr    = (const int*)d_in[2];
    const float* atom_emb = (const float*)d_in[3];
    const float* bond_emb = (const float*)d_in[4];
    const float* Wl  = (const float*)d_in[5];
    const float* bl  = (const float*)d_in[6];
    const float* Wr  = (const float*)d_in[7];
    const float* br  = (const float*)d_in[8];
    const float* We  = (const float*)d_in[9];
    const float* att = (const float*)d_in[10];
    const float* bias= (const float*)d_in[11];
    const float* Wa  = (const float*)d_in[12];
    const float* ba  = (const float*)d_in[13];
    const float* Wb  = (const float*)d_in[14];
    const float* bb  = (const float*)d_in[15];

    const int* src = edge_idx;
    const int* dst = edge_idx + NE;

    char* p = (char*)d_ws;
    auto alloc = [&](size_t bytes) -> void* {
        void* r = p; p += (bytes + 255) & ~(size_t)255; return r;
    };
    float*          h      = (float*)alloc((size_t)NN*DD*4);
    unsigned short* hb     = (unsigned short*)alloc((size_t)NN*DD*2);
    unsigned short* xlp    = (unsigned short*)alloc((size_t)NN*HC*2);
    unsigned short* xrp    = (unsigned short*)alloc((size_t)NN*HC*2);
    unsigned short* Wlrt   = (unsigned short*)alloc((size_t)NL*1024*DD*2);
    float*          blr    = (float*)alloc((size_t)NL*1024*4);
    unsigned short* Wat    = (unsigned short*)alloc((size_t)DD*VAv*2);
    unsigned short* Wbt    = (unsigned short*)alloc((size_t)16*256*2);
    __half*         eprojh = (__half*)alloc((size_t)NL*VBv*HC*2);
    int*            deg    = (int*)alloc((size_t)NN*4);
    int*            exc    = (int*)alloc((size_t)NN*4);
    int*            sums   = (int*)alloc(256*4);
    int*            rowptr = (int*)alloc((size_t)(NN+1)*4);
    int*            cnt    = (int*)alloc((size_t)NN*4);
    int*            packed = (int*)alloc((size_t)NE*4);

    float* atom_out = (float*)d_out;                      // [NN,128]
    float* bond_out = atom_out + (size_t)NN*VAv;          // [NE,16]

    hipMemsetAsync(deg, 0, (size_t)NN*4, stream);
    hipMemsetAsync(cnt, 0, (size_t)NN*4, stream);

    k_embed<<<7500, 256, 0, stream>>>(x, atom_emb, h, hb);
    k_convw<<<(NL*1024*DD + 255)/256, 256, 0, stream>>>(Wl, Wr, bl, br, Wlrt, blr);
    k_convwa<<<(DD*VAv + 255)/256, 256, 0, stream>>>(Wa, Wat);
    k_convwb<<<16, 256, 0, stream>>>(Wb, Wbt);
    k_eproj<<<(NL*VBv*HC + 255)/256, 256, 0, stream>>>(bond_emb, We, eprojh);

    // CSR by dst
    int nchunks = (NN + SCAN_CHUNK - 1) / SCAN_CHUNK;     // 118
    k_deg<<<(NE+255)/256, 256, 0, stream>>>(dst, deg);
    k_scan1<<<nchunks, SCAN_CHUNK, 0, stream>>>(deg, exc, sums);
    k_scan2<<<1, 128, 0, stream>>>(sums, nchunks);
    k_scan3<<<(NN+256)/256, 256, 0, stream>>>(exc, sums, rowptr);
    k_scatter<<<(NE+255)/256, 256, 0, stream>>>(src, dst, eattr, rowptr, cnt, packed);

    const int MTILES = (NN + 127) / 128;                  // 469
    const int GRP4 = (MTILES + 3) / 4;                    // 118 panels (MT=4)
    const int GRP2 = (MTILES + 1) / 2;                    // 235 panels (MT=2)
    const int SWZ_BLKS = ((GRP4 + 7) / 8) * 64;           // 960 (15 octets x 64)
    for (int l = 0; l < NL; ++l) {
        const float* att_l  = att  + (size_t)l*NH*VAv;
        const float* bias_l = bias + (size_t)l*DD;
        const unsigned short* Wlrt_l = Wlrt + (size_t)l*1024*DD;
        const float* blr_l = blr + (size_t)l*1024;
        const __half* ep_l = eprojh + (size_t)l*VBv*HC;

        k_gemm_mfma<2, 4, true><<<SWZ_BLKS, 256, 0, stream>>>(hb, Wlrt_l, blr_l, xlp, xrp, NN, 1024, GRP4);
        k_aggregate<<<2500, 512, 0, stream>>>(xlp, xrp, ep_l, rowptr, packed, att_l, bias_l, h, hb);
    }

    k_gemm_mfma<0, 2, false><<<dim3(VAv/128, GRP2), 256, 0, stream>>>(hb, Wat, ba, atom_out, nullptr, NN, VAv, GRP2);
    k_bond<<<NE/64, 256, 0, stream>>>(hb, src, dst, Wbt, bb, bond_out);
}

// Round 14
// 404.948 us; speedup vs baseline: 1.0321x; 1.0321x over previous
//
#include <hip/hip_runtime.h>
#include <hip/hip_bf16.h>
#include <hip/hip_fp16.h>
#include <math.h>

#define NN 60000
#define NE 200000
#define DD 128
#define NH 4
#define HC 512   // NH * C
#define NL 3
#define VAv 128
#define VBv 16
#define SCAN_CHUNK 512

typedef __attribute__((ext_vector_type(8))) short bf16x8;
typedef __attribute__((ext_vector_type(4))) float f32x4;
typedef _Float16 h2 __attribute__((ext_vector_type(2)));
typedef __fp16 fp16x2 __attribute__((ext_vector_type(2)));

__device__ __forceinline__ float bf2f(unsigned short u){
    union{unsigned int i; float f;} v; v.i = ((unsigned int)u)<<16; return v.f;
}
__device__ __forceinline__ unsigned short f2bf(float f){
    union{float f; unsigned int i;} v; v.f = f;
    unsigned int r = v.i + 0x7fffu + ((v.i>>16)&1u);
    return (unsigned short)(r>>16);
}
__device__ __forceinline__ h2 as_h2(unsigned int u){
    union{unsigned int x; h2 h;} c; c.x = u; return c.h;
}
__device__ __forceinline__ unsigned int pkrtz_u(float a, float b){
    union{fp16x2 h; unsigned int x;} c; c.h = __builtin_amdgcn_cvt_pkrtz(a, b); return c.x;
}

#define GLOAD_LDS16(g, l) \
    __builtin_amdgcn_global_load_lds((const __attribute__((address_space(1))) void*)(g), \
                                     (__attribute__((address_space(3))) void*)(l), 16, 0, 0)

// ---------------- embedding gather: h[n,:] = atom_emb[x[n],:] (fp32 + bf16) ----------
__global__ void k_embed(const int* __restrict__ x, const float* __restrict__ atom_emb,
                        float* __restrict__ h, unsigned short* __restrict__ hb) {
    int idx = blockIdx.x*blockDim.x + threadIdx.x;   // float4 index
    if (idx >= NN*(DD/4)) return;
    int n = idx >> 5;
    int c4 = idx & 31;
    int a = x[n];
    float4 v = ((const float4*)(atom_emb + (size_t)a*DD))[c4];
    ((float4*)(h + (size_t)n*DD))[c4] = v;
    ushort4 u = make_ushort4(f2bf(v.x), f2bf(v.y), f2bf(v.z), f2bf(v.w));
    ((ushort4*)(hb + (size_t)n*DD))[c4] = u;
}

// -------- weight convert: [Wl|Wr] -> Wlrt[l][1024][128] bf16 transposed; blr ---------
__global__ void k_convw(const float* __restrict__ Wl, const float* __restrict__ Wr,
                        const float* __restrict__ bl, const float* __restrict__ br,
                        unsigned short* __restrict__ Wlrt, float* __restrict__ blr) {
    int t = blockIdx.x*256 + threadIdx.x;
    if (t < NL*1024*DD) {
        int l = t / (1024*DD);
        int r = t % (1024*DD);
        int n = r / DD;      // 0..1023
        int k = r % DD;
        float v = (n < HC) ? Wl[(size_t)l*DD*HC + (size_t)k*HC + n]
                           : Wr[(size_t)l*DD*HC + (size_t)k*HC + (n - HC)];
        Wlrt[t] = f2bf(v);
    }
    if (t < NL*1024) {
        int l = t / 1024, j = t % 1024;
        blr[t] = (j < HC) ? bl[(size_t)l*HC + j] : br[(size_t)l*HC + (j - HC)];
    }
}

// ---------------- Wa convert: fp32 [128][128] -> bf16 transposed ---------------------
__global__ void k_convwa(const float* __restrict__ Wa, unsigned short* __restrict__ Wat) {
    int t = blockIdx.x*256 + threadIdx.x;
    if (t >= DD*VAv) return;
    int n = t / DD;
    int k = t % DD;
    Wat[t] = f2bf(Wa[(size_t)k*VAv + n]);
}

// ---------------- Wb convert: fp32 [256][16] -> Wbt bf16 [16][256] -------------------
__global__ void k_convwb(const float* __restrict__ Wb, unsigned short* __restrict__ Wbt) {
    int t = blockIdx.x*256 + threadIdx.x;
    if (t >= 16*256) return;
    int c = t >> 8, k = t & 255;
    Wbt[t] = f2bf(Wb[(size_t)k*16 + c]);
}

// -------- eproj (all layers): f16 linear [l][v][n] -----------------------------------
__global__ void k_eproj(const float* __restrict__ bond_emb, const float* __restrict__ We,
                        __half* __restrict__ eprojh) {
    int t = blockIdx.x*256 + threadIdx.x;    // 24576 total
    if (t >= NL*VBv*HC) return;
    int n = t & (HC-1);
    int v = (t >> 9) & (VBv-1);
    int l = t >> 13;
    const float* be = bond_emb + (size_t)v*DD;         // wave-uniform -> scalar
    const float* w  = We + (size_t)l*DD*HC + n;
    float acc = 0.f;
    #pragma unroll 8
    for (int k = 0; k < DD; ++k) acc = fmaf(be[k], w[(size_t)k*HC], acc);
    eprojh[t] = __float2half(acc);
}

// ---------------- CSR build ----------------
__global__ void k_deg(const int* __restrict__ dst, int* __restrict__ deg) {
    int e = blockIdx.x*blockDim.x + threadIdx.x;
    if (e < NE) atomicAdd(&deg[dst[e]], 1);
}

__global__ void k_scan1(const int* __restrict__ deg, int* __restrict__ exc, int* __restrict__ sums) {
    __shared__ int buf[2][SCAN_CHUNK];
    int t = threadIdx.x;
    int gi = blockIdx.x*SCAN_CHUNK + t;
    int v = (gi < NN) ? deg[gi] : 0;
    buf[0][t] = v;
    __syncthreads();
    int cur = 0;
    for (int off = 1; off < SCAN_CHUNK; off <<= 1) {
        int nv = buf[cur][t] + ((t >= off) ? buf[cur][t-off] : 0);
        buf[cur^1][t] = nv;
        __syncthreads();
        cur ^= 1;
    }
    if (gi < NN) exc[gi] = buf[cur][t] - v;
    if (t == SCAN_CHUNK-1) sums[blockIdx.x] = buf[cur][t];
}

__global__ void k_scan2(int* sums, int nb) {     // nb <= 128
    __shared__ int buf[2][128];
    int t = threadIdx.x;
    int v = (t < nb) ? sums[t] : 0;
    buf[0][t] = v;
    __syncthreads();
    int cur = 0;
    for (int off = 1; off < 128; off <<= 1) {
        int nv = buf[cur][t] + ((t >= off) ? buf[cur][t-off] : 0);
        buf[cur^1][t] = nv;
        __syncthreads();
        cur ^= 1;
    }
    if (t < nb) sums[t] = buf[cur][t] - v;       // exclusive
}

__global__ void k_scan3(const int* __restrict__ exc, const int* __restrict__ sums,
                        int* __restrict__ rowptr) {
    int i = blockIdx.x*blockDim.x + threadIdx.x;
    if (i < NN) rowptr[i] = exc[i] + sums[i / SCAN_CHUNK];
    if (i == NN) rowptr[NN] = NE;
}

// scatter: store src | (eattr<<16) sorted by dst  (src < 65536, eattr < 16)
__global__ void k_scatter(const int* __restrict__ srcv, const int* __restrict__ dst,
                          const int* __restrict__ eattr, const int* __restrict__ rowptr,
                          int* __restrict__ cnt, int* __restrict__ packed) {
    int e = blockIdx.x*blockDim.x + threadIdx.x;
    if (e < NE) {
        int d = dst[e];
        int pos = atomicAdd(&cnt[d], 1);
        packed[rowptr[d] + pos] = srcv[e] | (eattr[e] << 16);
    }
}

// ---------------- MFMA bf16 GEMM: OM=0 fp32 out, OM=2 f16 out ------------------------
template<int OM, int MT, bool SWZ>
__global__ __launch_bounds__(256)
void k_gemm_mfma(const unsigned short* __restrict__ A,
                 const unsigned short* __restrict__ Bt,
                 const float* __restrict__ bias, void* __restrict__ Cout,
                 int M, int Nc, int NP) {
    __shared__ unsigned short As[2][128*128];      // 64 KB
    const int tid = threadIdx.x;
    const int lane = tid & 63;
    const int wave = tid >> 6;

    int bn, bm0;
    if (SWZ) {
        int F = blockIdx.x;
        int P = (F & 7) + ((F >> 6) << 3);
        if (P >= NP) return;
        bn  = ((F >> 3) & 7) * 128;
        bm0 = P * (128*MT);
    } else {
        bn  = blockIdx.x * 128;
        bm0 = blockIdx.y * (128*MT);
    }

    const int l15 = lane & 15;
    const int l4  = lane >> 4;
    const int wm = (wave >> 1) * 64;
    const int wn = (wave & 1) * 64;

    // B fragments once (L2-hot), reused across all MT tiles
    bf16x8 bfr[4][4];
    #pragma unroll
    for (int ks = 0; ks < 4; ++ks)
        #pragma unroll
        for (int ni = 0; ni < 4; ++ni)
            bfr[ks][ni] = *(const bf16x8*)(Bt + (size_t)(bn + wn + ni*16 + l15)*128
                                              + (size_t)(ks*4 + l4)*8);

    float4 bv[4];
    #pragma unroll
    for (int ni = 0; ni < 4; ++ni)
        bv[ni] = bias ? *(const float4*)(bias + bn + wn + ni*16 + l4*4)
                      : make_float4(0.f, 0.f, 0.f, 0.f);

    auto stage = [&](int buf, int bm) {
        #pragma unroll
        for (int it = 0; it < 8; ++it) {
            int slot = it*256 + tid;        // 16B-chunk slot, 2048 per tile
            int row  = slot >> 4;
            int cph  = slot & 15;
            int clog = cph ^ (row & 15);
            int arow = bm + row; if (arow >= M) arow = M - 1;
            unsigned short* ldst = &As[buf][(size_t)(it*256 + (tid & ~63))*8];
            GLOAD_LDS16(A + (size_t)arow*128 + clog*8, ldst);
        }
    };

    stage(0, bm0);
    asm volatile("s_waitcnt vmcnt(0)" ::: "memory");
    __syncthreads();

    int cur = 0;
    for (int t = 0; t < MT; ++t) {
        int bm = bm0 + t*128;
        if (bm >= M) break;
        bool pf = (t+1 < MT) && (bm + 128 < M);
        if (pf) stage(cur^1, bm + 128);            // 8 DMA loads in flight

        f32x4 acc[4][4];
        #pragma unroll
        for (int i = 0; i < 4; ++i)
            #pragma unroll
            for (int j = 0; j < 4; ++j)
                acc[i][j] = (f32x4){0.f, 0.f, 0.f, 0.f};

        #pragma unroll
        for (int ks = 0; ks < 4; ++ks) {
            bf16x8 af[4];
            int cph = (ks*4 + l4) ^ l15;           // row&15 == l15 for fragment rows
            #pragma unroll
            for (int mi = 0; mi < 4; ++mi) {
                int row = wm + mi*16 + l15;
                af[mi] = *(const bf16x8*)(&As[cur][(size_t)row*128 + cph*8]);
            }
            #pragma unroll
            for (int mi = 0; mi < 4; ++mi)
                #pragma unroll
                for (int ni = 0; ni < 4; ++ni)
                    acc[mi][ni] = __builtin_amdgcn_mfma_f32_16x16x32_bf16(bfr[ks][ni], af[mi], acc[mi][ni], 0, 0, 0);
        }

        // epilogue: row = bm+wm+mi*16+l15; cols = bn+wn+ni*16+l4*4 .. +3
        #pragma unroll
        for (int mi = 0; mi < 4; ++mi) {
            int row = bm + wm + mi*16 + l15;
            bool rok = (row < M);
            #pragma unroll
            for (int ni = 0; ni < 4; ++ni) {
                float v0 = acc[mi][ni][0] + bv[ni].x;
                float v1 = acc[mi][ni][1] + bv[ni].y;
                float v2 = acc[mi][ni][2] + bv[ni].z;
                float v3 = acc[mi][ni][3] + bv[ni].w;
                int colb = bn + wn + ni*16 + l4*4;
                if (rok) {
                    if (OM == 2) {
                        *(uint2*)((unsigned short*)Cout + (size_t)row*Nc + colb)
                            = make_uint2(pkrtz_u(v0, v1), pkrtz_u(v2, v3));
                    } else {
                        *(float4*)((float*)Cout + (size_t)row*Nc + colb) = make_float4(v0, v1, v2, v3);
                    }
                }
            }
        }

        if (pf) {
            asm volatile("s_waitcnt vmcnt(16)" ::: "memory");
            __builtin_amdgcn_s_barrier();          // all waves done reading As[cur]
        }
        cur ^= 1;
    }
}

// ---- fused edge-logits + softmax + aggregate + epilogue (packed f16 math) ----------
// 8 waves/block, one node per wave, grid-stride. Lane l: channels l*8..+8 (f16).
// xlr row: [xl 512 | xr 512] f16. eps: 16KB LDS, 1KB/row, lane-stride-16B b128 reads.
__global__ __launch_bounds__(512)
void k_aggregate(const unsigned short* __restrict__ xlr,
                 const __half* __restrict__ eprojh,  // [16][512] f16, this layer
                 const int* __restrict__ rowptr, const int* __restrict__ packed,
                 const float* __restrict__ att,      // [4][128], this layer
                 const float* __restrict__ bias,     // [128], this layer
                 float* __restrict__ h, unsigned short* __restrict__ hb) {
    __shared__ uint4 eps4[1024];                     // 16 KB
    {
        const uint4* s4 = (const uint4*)eprojh;
        int t = threadIdx.x;
        eps4[t]       = s4[t];
        eps4[t + 512] = s4[t + 512];
    }
    __syncthreads();

    const int wave = threadIdx.x >> 6;
    const int lane = threadIdx.x & 63;
    const int loff = lane*8;                         // ushort index into row
    const h2 k02 = {(_Float16)0.2f, (_Float16)0.2f};

    h2 attf[4];
    {
        float4 a0 = *(const float4*)(att + loff);
        float4 a1 = *(const float4*)(att + loff + 4);
        attf[0] = (h2){(_Float16)a0.x, (_Float16)a0.y};
        attf[1] = (h2){(_Float16)a0.z, (_Float16)a0.w};
        attf[2] = (h2){(_Float16)a1.x, (_Float16)a1.y};
        attf[3] = (h2){(_Float16)a1.z, (_Float16)a1.w};
    }

#define EDGE_PROC(xr_, er_) do {                                            \
        h2 x0 = as_h2(xr_.x), x1 = as_h2(xr_.y);                            \
        h2 x2 = as_h2(xr_.z), x3 = as_h2(xr_.w);                            \
        h2 z0 = x0 + xrf[0] + as_h2(er_.x);                                 \
        h2 z1 = x1 + xrf[1] + as_h2(er_.y);                                 \
        h2 z2 = x2 + xrf[2] + as_h2(er_.z);                                 \
        h2 z3 = x3 + xrf[3] + as_h2(er_.w);                                 \
        h2 lacc = __builtin_elementwise_max(z0, z0*k02) * attf[0];          \
        lacc += __builtin_elementwise_max(z1, z1*k02) * attf[1];            \
        lacc += __builtin_elementwise_max(z2, z2*k02) * attf[2];            \
        lacc += __builtin_elementwise_max(z3, z3*k02) * attf[3];            \
        float pz_ = (float)lacc[0] + (float)lacc[1];                        \
        pz_ += __shfl_xor(pz_, 1);                                          \
        pz_ += __shfl_xor(pz_, 2);                                          \
        pz_ += __shfl_xor(pz_, 4);                                          \
        pz_ += __shfl_xor(pz_, 8);                                          \
        float w_ = __expf(pz_);                                             \
        wsum += w_;                                                         \
        h2 wh = {(_Float16)w_, (_Float16)w_};                               \
        acc0 += wh*x0; acc1 += wh*x1; acc2 += wh*x2; acc3 += wh*x3;         \
    } while (0)

    for (int g = blockIdx.x; g < NN/8; g += gridDim.x) {
        int n = g*8 + wave;

        h2 xrf[4];
        {
            uint4 raw = *(const uint4*)(xlr + (size_t)n*1024 + 512 + loff);
            xrf[0] = as_h2(raw.x); xrf[1] = as_h2(raw.y);
            xrf[2] = as_h2(raw.z); xrf[3] = as_h2(raw.w);
        }

        h2 acc0 = {0,0}, acc1 = {0,0}, acc2 = {0,0}, acc3 = {0,0};
        float wsum = 0.f;
        int beg = rowptr[n], end = rowptr[n+1];
        int p = beg;

        for (; p + 4 <= end; p += 4) {               // 4 edges in flight
            int pk0 = packed[p],   pk1 = packed[p+1];
            int pk2 = packed[p+2], pk3 = packed[p+3];
            uint4 v0 = *(const uint4*)(xlr + (size_t)(pk0 & 0xFFFF)*1024 + loff);
            uint4 v1 = *(const uint4*)(xlr + (size_t)(pk1 & 0xFFFF)*1024 + loff);
            uint4 v2 = *(const uint4*)(xlr + (size_t)(pk2 & 0xFFFF)*1024 + loff);
            uint4 v3 = *(const uint4*)(xlr + (size_t)(pk3 & 0xFFFF)*1024 + loff);
            uint4 e0 = eps4[(pk0 >> 16)*64 + lane];
            uint4 e1 = eps4[(pk1 >> 16)*64 + lane];
            uint4 e2 = eps4[(pk2 >> 16)*64 + lane];
            uint4 e3 = eps4[(pk3 >> 16)*64 + lane];
            EDGE_PROC(v0, e0);
            EDGE_PROC(v1, e1);
            EDGE_PROC(v2, e2);
            EDGE_PROC(v3, e3);
        }
        if (p + 2 <= end) {                          // 2-wide tail
            int pk0 = packed[p], pk1 = packed[p+1];
            uint4 v0 = *(const uint4*)(xlr + (size_t)(pk0 & 0xFFFF)*1024 + loff);
            uint4 v1 = *(const uint4*)(xlr + (size_t)(pk1 & 0xFFFF)*1024 + loff);
            uint4 e0 = eps4[(pk0 >> 16)*64 + lane];
            uint4 e1 = eps4[(pk1 >> 16)*64 + lane];
            EDGE_PROC(v0, e0);
            EDGE_PROC(v1, e1);
            p += 2;
        }
        if (p < end) {                               // 1-wide tail
            int pk0 = packed[p];
            uint4 v0 = *(const uint4*)(xlr + (size_t)(pk0 & 0xFFFF)*1024 + loff);
            uint4 e0 = eps4[(pk0 >> 16)*64 + lane];
            EDGE_PROC(v0, e0);
        }

        float inv = __builtin_amdgcn_rcpf(wsum + 1e-16f);
        float rr[8];
        rr[0] = (float)acc0[0]; rr[1] = (float)acc0[1];
        rr[2] = (float)acc1[0]; rr[3] = (float)acc1[1];
        rr[4] = (float)acc2[0]; rr[5] = (float)acc2[1];
        rr[6] = (float)acc3[0]; rr[7] = (float)acc3[1];
        #pragma unroll
        for (int u = 0; u < 8; ++u) rr[u] *= inv;
        #pragma unroll
        for (int u = 0; u < 8; ++u) rr[u] += __shfl_xor(rr[u], 16);
        #pragma unroll
        for (int u = 0; u < 8; ++u) rr[u] += __shfl_xor(rr[u], 32);

        if (lane < 16) {
            int c = lane*8;
            float* hp = h + (size_t)n*DD + c;
            float4 h0 = *(const float4*)hp;
            float4 h1 = *(const float4*)(hp + 4);
            float4 b0 = *(const float4*)(bias + c);
            float4 b1 = *(const float4*)(bias + c + 4);
            float o[8];
            o[0] = h0.x + fmaxf(0.f, fmaf(0.25f, rr[0], b0.x));
            o[1] = h0.y + fmaxf(0.f, fmaf(0.25f, rr[1], b0.y));
            o[2] = h0.z + fmaxf(0.f, fmaf(0.25f, rr[2], b0.z));
            o[3] = h0.w + fmaxf(0.f, fmaf(0.25f, rr[3], b0.w));
            o[4] = h1.x + fmaxf(0.f, fmaf(0.25f, rr[4], b1.x));
            o[5] = h1.y + fmaxf(0.f, fmaf(0.25f, rr[5], b1.y));
            o[6] = h1.z + fmaxf(0.f, fmaf(0.25f, rr[6], b1.z));
            o[7] = h1.w + fmaxf(0.f, fmaf(0.25f, rr[7], b1.w));
            *(float4*)hp       = make_float4(o[0], o[1], o[2], o[3]);
            *(float4*)(hp + 4) = make_float4(o[4], o[5], o[6], o[7]);
            ushort4 u0 = make_ushort4(f2bf(o[0]), f2bf(o[1]), f2bf(o[2]), f2bf(o[3]));
            ushort4 u1 = make_ushort4(f2bf(o[4]), f2bf(o[5]), f2bf(o[6]), f2bf(o[7]));
            unsigned short* hbp = hb + (size_t)n*DD + c;
            *(ushort4*)hbp       = u0;
            *(ushort4*)(hbp + 4) = u1;
        }
    }
#undef EDGE_PROC
}

// ---------------- bond head v2: MFMA, wave = 16 edges ---------------------------------
__global__ __launch_bounds__(256)
void k_bond(const unsigned short* __restrict__ hb,
            const int* __restrict__ srcv, const int* __restrict__ dstv,
            const unsigned short* __restrict__ Wbt, const float* __restrict__ bb,
            float* __restrict__ out) {
    int lane = threadIdx.x & 63;
    int wave = threadIdx.x >> 6;
    int ebase = blockIdx.x*64 + wave*16;     // NE = 200000 = 3125*64 exact
    int l15 = lane & 15, l4 = lane >> 4;
    int e = ebase + l15;
    const unsigned short* hs = hb + (size_t)srcv[e]*DD;
    const unsigned short* hd = hb + (size_t)dstv[e]*DD;

    bf16x8 bfr[8];
    #pragma unroll
    for (int s = 0; s < 8; ++s)
        bfr[s] = *(const bf16x8*)(Wbt + l15*256 + s*32 + l4*8);

    float bbv = bb[l15];
    f32x4 acc = (f32x4){bbv, bbv, bbv, bbv};
    #pragma unroll
    for (int s = 0; s < 4; ++s) {
        bf16x8 af = *(const bf16x8*)(hs + s*32 + l4*8);
        acc = __builtin_amdgcn_mfma_f32_16x16x32_bf16(af, bfr[s], acc, 0, 0, 0);
    }
    #pragma unroll
    for (int s = 0; s < 4; ++s) {
        bf16x8 af = *(const bf16x8*)(hd + s*32 + l4*8);
        acc = __builtin_amdgcn_mfma_f32_16x16x32_bf16(af, bfr[4+s], acc, 0, 0, 0);
    }
    #pragma unroll
    for (int r = 0; r < 4; ++r)
        out[(size_t)(ebase + l4*4 + r)*16 + l15] = acc[r];
}

// ---------------- host ----------------
extern "C" void kernel_launch(void* const* d_in, const int* in_sizes, int n_in,
                              void* d_out, int out_size, void* d_ws, size_t ws_size,
                              hipStream_t stream) {
    const int*   x        = (const int*)d_in[0];
    const int*   edge_idx = (const int*)d_in[1];
    const int*   eattr    = (const int*)d_in[2];
    const float* atom_emb = (const float*)d_in[3];
    const float* bond_emb = (const float*)d_in[4];
    const float* Wl  = (const float*)d_in[5];
    const float* bl  = (const float*)d_in[6];
    const float* Wr  = (const float*)d_in[7];
    const float* br  = (const float*)d_in[8];
    const float* We  = (const float*)d_in[9];
    const float* att = (const float*)d_in[10];
    const float* bias= (const float*)d_in[11];
    const float* Wa  = (const float*)d_in[12];
    const float* ba  = (const float*)d_in[13];
    const float* Wb  = (const float*)d_in[14];
    const float* bb  = (const float*)d_in[15];

    const int* src = edge_idx;
    const int* dst = edge_idx + NE;

    char* p = (char*)d_ws;
    auto alloc = [&](size_t bytes) -> void* {
        void* r = p; p += (bytes + 255) & ~(size_t)255; return r;
    };
    float*          h      = (float*)alloc((size_t)NN*DD*4);
    unsigned short* hb     = (unsigned short*)alloc((size_t)NN*DD*2);
    unsigned short* xlr    = (unsigned short*)alloc((size_t)NN*1024*2);
    unsigned short* Wlrt   = (unsigned short*)alloc((size_t)NL*1024*DD*2);
    float*          blr    = (float*)alloc((size_t)NL*1024*4);
    unsigned short* Wat    = (unsigned short*)alloc((size_t)DD*VAv*2);
    unsigned short* Wbt    = (unsigned short*)alloc((size_t)16*256*2);
    __half*         eprojh = (__half*)alloc((size_t)NL*VBv*HC*2);
    int*            deg    = (int*)alloc((size_t)NN*4);
    int*            exc    = (int*)alloc((size_t)NN*4);
    int*            sums   = (int*)alloc(256*4);
    int*            rowptr = (int*)alloc((size_t)(NN+1)*4);
    int*            cnt    = (int*)alloc((size_t)NN*4);
    int*            packed = (int*)alloc((size_t)NE*4);

    float* atom_out = (float*)d_out;                      // [NN,128]
    float* bond_out = atom_out + (size_t)NN*VAv;          // [NE,16]

    hipMemsetAsync(deg, 0, (size_t)NN*4, stream);
    hipMemsetAsync(cnt, 0, (size_t)NN*4, stream);

    k_embed<<<7500, 256, 0, stream>>>(x, atom_emb, h, hb);
    k_convw<<<(NL*1024*DD + 255)/256, 256, 0, stream>>>(Wl, Wr, bl, br, Wlrt, blr);
    k_convwa<<<(DD*VAv + 255)/256, 256, 0, stream>>>(Wa, Wat);
    k_convwb<<<16, 256, 0, stream>>>(Wb, Wbt);
    k_eproj<<<(NL*VBv*HC + 255)/256, 256, 0, stream>>>(bond_emb, We, eprojh);

    // CSR by dst
    int nchunks = (NN + SCAN_CHUNK - 1) / SCAN_CHUNK;     // 118
    k_deg<<<(NE+255)/256, 256, 0, stream>>>(dst, deg);
    k_scan1<<<nchunks, SCAN_CHUNK, 0, stream>>>(deg, exc, sums);
    k_scan2<<<1, 128, 0, stream>>>(sums, nchunks);
    k_scan3<<<(NN+256)/256, 256, 0, stream>>>(exc, sums, rowptr);
    k_scatter<<<(NE+255)/256, 256, 0, stream>>>(src, dst, eattr, rowptr, cnt, packed);

    const int MTILES = (NN + 127) / 128;                  // 469
    const int GRP4 = (MTILES + 3) / 4;                    // 118 panels (MT=4)
    const int GRP2 = (MTILES + 1) / 2;                    // 235 panels (MT=2)
    const int SWZ_BLKS = ((GRP4 + 7) / 8) * 64;           // 960 (15 octets x 64)
    for (int l = 0; l < NL; ++l) {
        const float* att_l  = att  + (size_t)l*NH*VAv;
        const float* bias_l = bias + (size_t)l*DD;
        const unsigned short* Wlrt_l = Wlrt + (size_t)l*1024*DD;
        const float* blr_l = blr + (size_t)l*1024;
        const __half* ep_l = eprojh + (size_t)l*VBv*HC;

        k_gemm_mfma<2, 4, true><<<SWZ_BLKS, 256, 0, stream>>>(hb, Wlrt_l, blr_l, xlr, NN, 1024, GRP4);
        k_aggregate<<<2500, 512, 0, stream>>>(xlr, ep_l, rowptr, packed, att_l, bias_l, h, hb);
    }

    k_gemm_mfma<0, 2, false><<<dim3(VAv/128, GRP2), 256, 0, stream>>>(hb, Wat, ba, atom_out, NN, VAv, GRP2);
    k_bond<<<NE/64, 256, 0, stream>>>(hb, src, dst, Wbt, bb, bond_out);
}

// Round 15
// 395.276 us; speedup vs baseline: 1.0574x; 1.0245x over previous
//
#include <hip/hip_runtime.h>
#include <hip/hip_bf16.h>
#include <hip/hip_fp16.h>
#include <math.h>

#define NN 60000
#define NE 200000
#define DD 128
#define NH 4
#define HC 512   // NH * C
#define NL 3
#define VAv 128
#define VBv 16
#define SCAN_CHUNK 512

typedef __attribute__((ext_vector_type(8))) short bf16x8;
typedef __attribute__((ext_vector_type(4))) float f32x4;
typedef _Float16 h2 __attribute__((ext_vector_type(2)));
typedef __fp16 fp16x2 __attribute__((ext_vector_type(2)));

__device__ __forceinline__ float bf2f(unsigned short u){
    union{unsigned int i; float f;} v; v.i = ((unsigned int)u)<<16; return v.f;
}
__device__ __forceinline__ unsigned short f2bf(float f){
    union{float f; unsigned int i;} v; v.f = f;
    unsigned int r = v.i + 0x7fffu + ((v.i>>16)&1u);
    return (unsigned short)(r>>16);
}
__device__ __forceinline__ h2 as_h2(unsigned int u){
    union{unsigned int x; h2 h;} c; c.x = u; return c.h;
}
__device__ __forceinline__ unsigned int pkrtz_u(float a, float b){
    union{fp16x2 h; unsigned int x;} c; c.h = __builtin_amdgcn_cvt_pkrtz(a, b); return c.x;
}

#define GLOAD_LDS16(g, l) \
    __builtin_amdgcn_global_load_lds((const __attribute__((address_space(1))) void*)(g), \
                                     (__attribute__((address_space(3))) void*)(l), 16, 0, 0)

// ---------------- embedding gather: h[n,:] = atom_emb[x[n],:] (fp32 + bf16) ----------
__global__ void k_embed(const int* __restrict__ x, const float* __restrict__ atom_emb,
                        float* __restrict__ h, unsigned short* __restrict__ hb) {
    int idx = blockIdx.x*blockDim.x + threadIdx.x;   // float4 index
    if (idx >= NN*(DD/4)) return;
    int n = idx >> 5;
    int c4 = idx & 31;
    int a = x[n];
    float4 v = ((const float4*)(atom_emb + (size_t)a*DD))[c4];
    ((float4*)(h + (size_t)n*DD))[c4] = v;
    ushort4 u = make_ushort4(f2bf(v.x), f2bf(v.y), f2bf(v.z), f2bf(v.w));
    ((ushort4*)(hb + (size_t)n*DD))[c4] = u;
}

// -------- weight convert: [Wl|Wr] -> Wlrt[l][1024][128] bf16 transposed; blr ---------
__global__ void k_convw(const float* __restrict__ Wl, const float* __restrict__ Wr,
                        const float* __restrict__ bl, const float* __restrict__ br,
                        unsigned short* __restrict__ Wlrt, float* __restrict__ blr) {
    int t = blockIdx.x*256 + threadIdx.x;
    if (t < NL*1024*DD) {
        int l = t / (1024*DD);
        int r = t % (1024*DD);
        int n = r / DD;      // 0..1023
        int k = r % DD;
        float v = (n < HC) ? Wl[(size_t)l*DD*HC + (size_t)k*HC + n]
                           : Wr[(size_t)l*DD*HC + (size_t)k*HC + (n - HC)];
        Wlrt[t] = f2bf(v);
    }
    if (t < NL*1024) {
        int l = t / 1024, j = t % 1024;
        blr[t] = (j < HC) ? bl[(size_t)l*HC + j] : br[(size_t)l*HC + (j - HC)];
    }
}

// ---------------- Wa convert: fp32 [128][128] -> bf16 transposed ---------------------
__global__ void k_convwa(const float* __restrict__ Wa, unsigned short* __restrict__ Wat) {
    int t = blockIdx.x*256 + threadIdx.x;
    if (t >= DD*VAv) return;
    int n = t / DD;
    int k = t % DD;
    Wat[t] = f2bf(Wa[(size_t)k*VAv + n]);
}

// ---------------- Wb convert: fp32 [256][16] -> Wbt bf16 [16][256] -------------------
__global__ void k_convwb(const float* __restrict__ Wb, unsigned short* __restrict__ Wbt) {
    int t = blockIdx.x*256 + threadIdx.x;
    if (t >= 16*256) return;
    int c = t >> 8, k = t & 255;
    Wbt[t] = f2bf(Wb[(size_t)k*16 + c]);
}

// -------- eproj (all layers): f16 linear [l][v][n] -----------------------------------
__global__ void k_eproj(const float* __restrict__ bond_emb, const float* __restrict__ We,
                        __half* __restrict__ eprojh) {
    int t = blockIdx.x*256 + threadIdx.x;    // 24576 total
    if (t >= NL*VBv*HC) return;
    int n = t & (HC-1);
    int v = (t >> 9) & (VBv-1);
    int l = t >> 13;
    const float* be = bond_emb + (size_t)v*DD;         // wave-uniform -> scalar
    const float* w  = We + (size_t)l*DD*HC + n;
    float acc = 0.f;
    #pragma unroll 8
    for (int k = 0; k < DD; ++k) acc = fmaf(be[k], w[(size_t)k*HC], acc);
    eprojh[t] = __float2half(acc);
}

// ---------------- CSR build ----------------
__global__ void k_deg(const int* __restrict__ dst, int* __restrict__ deg) {
    int e = blockIdx.x*blockDim.x + threadIdx.x;
    if (e < NE) atomicAdd(&deg[dst[e]], 1);
}

__global__ void k_scan1(const int* __restrict__ deg, int* __restrict__ exc, int* __restrict__ sums) {
    __shared__ int buf[2][SCAN_CHUNK];
    int t = threadIdx.x;
    int gi = blockIdx.x*SCAN_CHUNK + t;
    int v = (gi < NN) ? deg[gi] : 0;
    buf[0][t] = v;
    __syncthreads();
    int cur = 0;
    for (int off = 1; off < SCAN_CHUNK; off <<= 1) {
        int nv = buf[cur][t] + ((t >= off) ? buf[cur][t-off] : 0);
        buf[cur^1][t] = nv;
        __syncthreads();
        cur ^= 1;
    }
    if (gi < NN) exc[gi] = buf[cur][t] - v;
    if (t == SCAN_CHUNK-1) sums[blockIdx.x] = buf[cur][t];
}

__global__ void k_scan2(int* sums, int nb) {     // nb <= 128
    __shared__ int buf[2][128];
    int t = threadIdx.x;
    int v = (t < nb) ? sums[t] : 0;
    buf[0][t] = v;
    __syncthreads();
    int cur = 0;
    for (int off = 1; off < 128; off <<= 1) {
        int nv = buf[cur][t] + ((t >= off) ? buf[cur][t-off] : 0);
        buf[cur^1][t] = nv;
        __syncthreads();
        cur ^= 1;
    }
    if (t < nb) sums[t] = buf[cur][t] - v;       // exclusive
}

__global__ void k_scan3(const int* __restrict__ exc, const int* __restrict__ sums,
                        int* __restrict__ rowptr) {
    int i = blockIdx.x*blockDim.x + threadIdx.x;
    if (i < NN) rowptr[i] = exc[i] + sums[i / SCAN_CHUNK];
    if (i == NN) rowptr[NN] = NE;
}

// scatter: store src | (eattr<<16) sorted by dst  (src < 65536, eattr < 16)
__global__ void k_scatter(const int* __restrict__ srcv, const int* __restrict__ dst,
                          const int* __restrict__ eattr, const int* __restrict__ rowptr,
                          int* __restrict__ cnt, int* __restrict__ packed) {
    int e = blockIdx.x*blockDim.x + threadIdx.x;
    if (e < NE) {
        int d = dst[e];
        int pos = atomicAdd(&cnt[d], 1);
        packed[rowptr[d] + pos] = srcv[e] | (eattr[e] << 16);
    }
}

// ------- MFMA bf16 GEMM v6: 8-wave blocks (64x32 wave-tile) for 2x occupancy ---------
// OM=0 fp32 out, OM=2 f16 out. 512 threads, wave (wr=wave>>2, wc=wave&3) owns a
// 64x32 sub-tile: acc[4][2]+bfr[4][2] = 64 regs vs 128 -> ~104 regs/wave total.
// LDS 64 KB double-buffered -> 2 blocks/CU x 8 waves = 16 waves/CU (~50% occ).
template<int OM, int MT, bool SWZ>
__global__ __launch_bounds__(512)
void k_gemm_mfma(const unsigned short* __restrict__ A,
                 const unsigned short* __restrict__ Bt,
                 const float* __restrict__ bias, void* __restrict__ Cout,
                 int M, int Nc, int NP) {
    __shared__ unsigned short As[2][128*128];      // 64 KB
    const int tid = threadIdx.x;
    const int lane = tid & 63;
    const int wave = tid >> 6;                     // 0..7

    int bn, bm0;
    if (SWZ) {
        int F = blockIdx.x;
        int P = (F & 7) + ((F >> 6) << 3);
        if (P >= NP) return;
        bn  = ((F >> 3) & 7) * 128;
        bm0 = P * (128*MT);
    } else {
        bn  = blockIdx.x * 128;
        bm0 = blockIdx.y * (128*MT);
    }

    const int l15 = lane & 15;
    const int l4  = lane >> 4;
    const int wm = (wave >> 2) * 64;               // 0 or 64
    const int wn = (wave & 3) * 32;                // 0,32,64,96

    // B fragments once (L2-hot), reused across all MT tiles
    bf16x8 bfr[4][2];
    #pragma unroll
    for (int ks = 0; ks < 4; ++ks)
        #pragma unroll
        for (int ni = 0; ni < 2; ++ni)
            bfr[ks][ni] = *(const bf16x8*)(Bt + (size_t)(bn + wn + ni*16 + l15)*128
                                              + (size_t)(ks*4 + l4)*8);

    float4 bv[2];
    #pragma unroll
    for (int ni = 0; ni < 2; ++ni)
        bv[ni] = bias ? *(const float4*)(bias + bn + wn + ni*16 + l4*4)
                      : make_float4(0.f, 0.f, 0.f, 0.f);

    auto stage = [&](int buf, int bm) {
        #pragma unroll
        for (int it = 0; it < 4; ++it) {
            int slot = it*512 + tid;        // 16B-chunk slot, 2048 per tile
            int row  = slot >> 4;
            int cph  = slot & 15;
            int clog = cph ^ (row & 15);
            int arow = bm + row; if (arow >= M) arow = M - 1;
            unsigned short* ldst = &As[buf][(size_t)(it*512 + (tid & ~63))*8];
            GLOAD_LDS16(A + (size_t)arow*128 + clog*8, ldst);
        }
    };

    stage(0, bm0);
    asm volatile("s_waitcnt vmcnt(0)" ::: "memory");
    __syncthreads();

    int cur = 0;
    for (int t = 0; t < MT; ++t) {
        int bm = bm0 + t*128;
        if (bm >= M) break;
        bool pf = (t+1 < MT) && (bm + 128 < M);
        if (pf) stage(cur^1, bm + 128);            // 4 DMA loads in flight

        f32x4 acc[4][2];
        #pragma unroll
        for (int i = 0; i < 4; ++i)
            #pragma unroll
            for (int j = 0; j < 2; ++j)
                acc[i][j] = (f32x4){0.f, 0.f, 0.f, 0.f};

        #pragma unroll
        for (int ks = 0; ks < 4; ++ks) {
            bf16x8 af[4];
            int cph = (ks*4 + l4) ^ l15;           // row&15 == l15 for fragment rows
            #pragma unroll
            for (int mi = 0; mi < 4; ++mi) {
                int row = wm + mi*16 + l15;
                af[mi] = *(const bf16x8*)(&As[cur][(size_t)row*128 + cph*8]);
            }
            #pragma unroll
            for (int mi = 0; mi < 4; ++mi)
                #pragma unroll
                for (int ni = 0; ni < 2; ++ni)
                    acc[mi][ni] = __builtin_amdgcn_mfma_f32_16x16x32_bf16(bfr[ks][ni], af[mi], acc[mi][ni], 0, 0, 0);
        }

        // epilogue: row = bm+wm+mi*16+l15; cols = bn+wn+ni*16+l4*4 .. +3  (8 stores)
        #pragma unroll
        for (int mi = 0; mi < 4; ++mi) {
            int row = bm + wm + mi*16 + l15;
            bool rok = (row < M);
            #pragma unroll
            for (int ni = 0; ni < 2; ++ni) {
                float v0 = acc[mi][ni][0] + bv[ni].x;
                float v1 = acc[mi][ni][1] + bv[ni].y;
                float v2 = acc[mi][ni][2] + bv[ni].z;
                float v3 = acc[mi][ni][3] + bv[ni].w;
                int colb = bn + wn + ni*16 + l4*4;
                if (rok) {
                    if (OM == 2) {
                        *(uint2*)((unsigned short*)Cout + (size_t)row*Nc + colb)
                            = make_uint2(pkrtz_u(v0, v1), pkrtz_u(v2, v3));
                    } else {
                        *(float4*)((float*)Cout + (size_t)row*Nc + colb) = make_float4(v0, v1, v2, v3);
                    }
                }
            }
        }

        if (pf) {
            // newest 8 vmem ops are this tile's stores; ensures the 4 DMAs landed
            asm volatile("s_waitcnt vmcnt(8)" ::: "memory");
            __builtin_amdgcn_s_barrier();          // all waves done reading As[cur]
        }
        cur ^= 1;
    }
}

// ---- fused edge-logits + softmax + aggregate + epilogue (packed f16 math) ----------
// 8 waves/block, one node per wave, grid-stride. Lane l: channels l*8..+8 (f16).
// xlr row: [xl 512 | xr 512] f16. eps: 16KB LDS, 1KB/row, lane-stride-16B b128 reads.
__global__ __launch_bounds__(512)
void k_aggregate(const unsigned short* __restrict__ xlr,
                 const __half* __restrict__ eprojh,  // [16][512] f16, this layer
                 const int* __restrict__ rowptr, const int* __restrict__ packed,
                 const float* __restrict__ att,      // [4][128], this layer
                 const float* __restrict__ bias,     // [128], this layer
                 float* __restrict__ h, unsigned short* __restrict__ hb) {
    __shared__ uint4 eps4[1024];                     // 16 KB
    {
        const uint4* s4 = (const uint4*)eprojh;
        int t = threadIdx.x;
        eps4[t]       = s4[t];
        eps4[t + 512] = s4[t + 512];
    }
    __syncthreads();

    const int wave = threadIdx.x >> 6;
    const int lane = threadIdx.x & 63;
    const int loff = lane*8;                         // ushort index into row
    const h2 k02 = {(_Float16)0.2f, (_Float16)0.2f};

    h2 attf[4];
    {
        float4 a0 = *(const float4*)(att + loff);
        float4 a1 = *(const float4*)(att + loff + 4);
        attf[0] = (h2){(_Float16)a0.x, (_Float16)a0.y};
        attf[1] = (h2){(_Float16)a0.z, (_Float16)a0.w};
        attf[2] = (h2){(_Float16)a1.x, (_Float16)a1.y};
        attf[3] = (h2){(_Float16)a1.z, (_Float16)a1.w};
    }

#define EDGE_PROC(xr_, er_) do {                                            \
        h2 x0 = as_h2(xr_.x), x1 = as_h2(xr_.y);                            \
        h2 x2 = as_h2(xr_.z), x3 = as_h2(xr_.w);                            \
        h2 z0 = x0 + xrf[0] + as_h2(er_.x);                                 \
        h2 z1 = x1 + xrf[1] + as_h2(er_.y);                                 \
        h2 z2 = x2 + xrf[2] + as_h2(er_.z);                                 \
        h2 z3 = x3 + xrf[3] + as_h2(er_.w);                                 \
        h2 lacc = __builtin_elementwise_max(z0, z0*k02) * attf[0];          \
        lacc += __builtin_elementwise_max(z1, z1*k02) * attf[1];            \
        lacc += __builtin_elementwise_max(z2, z2*k02) * attf[2];            \
        lacc += __builtin_elementwise_max(z3, z3*k02) * attf[3];            \
        float pz_ = (float)lacc[0] + (float)lacc[1];                        \
        pz_ += __shfl_xor(pz_, 1);                                          \
        pz_ += __shfl_xor(pz_, 2);                                          \
        pz_ += __shfl_xor(pz_, 4);                                          \
        pz_ += __shfl_xor(pz_, 8);                                          \
        float w_ = __expf(pz_);                                             \
        wsum += w_;                                                         \
        h2 wh = {(_Float16)w_, (_Float16)w_};                               \
        acc0 += wh*x0; acc1 += wh*x1; acc2 += wh*x2; acc3 += wh*x3;         \
    } while (0)

    for (int g = blockIdx.x; g < NN/8; g += gridDim.x) {
        int n = g*8 + wave;

        h2 xrf[4];
        {
            uint4 raw = *(const uint4*)(xlr + (size_t)n*1024 + 512 + loff);
            xrf[0] = as_h2(raw.x); xrf[1] = as_h2(raw.y);
            xrf[2] = as_h2(raw.z); xrf[3] = as_h2(raw.w);
        }

        h2 acc0 = {0,0}, acc1 = {0,0}, acc2 = {0,0}, acc3 = {0,0};
        float wsum = 0.f;
        int beg = rowptr[n], end = rowptr[n+1];
        int p = beg;

        for (; p + 4 <= end; p += 4) {               // 4 edges in flight
            int pk0 = packed[p],   pk1 = packed[p+1];
            int pk2 = packed[p+2], pk3 = packed[p+3];
            uint4 v0 = *(const uint4*)(xlr + (size_t)(pk0 & 0xFFFF)*1024 + loff);
            uint4 v1 = *(const uint4*)(xlr + (size_t)(pk1 & 0xFFFF)*1024 + loff);
            uint4 v2 = *(const uint4*)(xlr + (size_t)(pk2 & 0xFFFF)*1024 + loff);
            uint4 v3 = *(const uint4*)(xlr + (size_t)(pk3 & 0xFFFF)*1024 + loff);
            uint4 e0 = eps4[(pk0 >> 16)*64 + lane];
            uint4 e1 = eps4[(pk1 >> 16)*64 + lane];
            uint4 e2 = eps4[(pk2 >> 16)*64 + lane];
            uint4 e3 = eps4[(pk3 >> 16)*64 + lane];
            EDGE_PROC(v0, e0);
            EDGE_PROC(v1, e1);
            EDGE_PROC(v2, e2);
            EDGE_PROC(v3, e3);
        }
        if (p + 2 <= end) {                          // 2-wide tail
            int pk0 = packed[p], pk1 = packed[p+1];
            uint4 v0 = *(const uint4*)(xlr + (size_t)(pk0 & 0xFFFF)*1024 + loff);
            uint4 v1 = *(const uint4*)(xlr + (size_t)(pk1 & 0xFFFF)*1024 + loff);
            uint4 e0 = eps4[(pk0 >> 16)*64 + lane];
            uint4 e1 = eps4[(pk1 >> 16)*64 + lane];
            EDGE_PROC(v0, e0);
            EDGE_PROC(v1, e1);
            p += 2;
        }
        if (p < end) {                               // 1-wide tail
            int pk0 = packed[p];
            uint4 v0 = *(const uint4*)(xlr + (size_t)(pk0 & 0xFFFF)*1024 + loff);
            uint4 e0 = eps4[(pk0 >> 16)*64 + lane];
            EDGE_PROC(v0, e0);
        }

        float inv = __builtin_amdgcn_rcpf(wsum + 1e-16f);
        float rr[8];
        rr[0] = (float)acc0[0]; rr[1] = (float)acc0[1];
        rr[2] = (float)acc1[0]; rr[3] = (float)acc1[1];
        rr[4] = (float)acc2[0]; rr[5] = (float)acc2[1];
        rr[6] = (float)acc3[0]; rr[7] = (float)acc3[1];
        #pragma unroll
        for (int u = 0; u < 8; ++u) rr[u] *= inv;
        #pragma unroll
        for (int u = 0; u < 8; ++u) rr[u] += __shfl_xor(rr[u], 16);
        #pragma unroll
        for (int u = 0; u < 8; ++u) rr[u] += __shfl_xor(rr[u], 32);

        if (lane < 16) {
            int c = lane*8;
            float* hp = h + (size_t)n*DD + c;
            float4 h0 = *(const float4*)hp;
            float4 h1 = *(const float4*)(hp + 4);
            float4 b0 = *(const float4*)(bias + c);
            float4 b1 = *(const float4*)(bias + c + 4);
            float o[8];
            o[0] = h0.x + fmaxf(0.f, fmaf(0.25f, rr[0], b0.x));
            o[1] = h0.y + fmaxf(0.f, fmaf(0.25f, rr[1], b0.y));
            o[2] = h0.z + fmaxf(0.f, fmaf(0.25f, rr[2], b0.z));
            o[3] = h0.w + fmaxf(0.f, fmaf(0.25f, rr[3], b0.w));
            o[4] = h1.x + fmaxf(0.f, fmaf(0.25f, rr[4], b1.x));
            o[5] = h1.y + fmaxf(0.f, fmaf(0.25f, rr[5], b1.y));
            o[6] = h1.z + fmaxf(0.f, fmaf(0.25f, rr[6], b1.z));
            o[7] = h1.w + fmaxf(0.f, fmaf(0.25f, rr[7], b1.w));
            *(float4*)hp       = make_float4(o[0], o[1], o[2], o[3]);
            *(float4*)(hp + 4) = make_float4(o[4], o[5], o[6], o[7]);
            ushort4 u0 = make_ushort4(f2bf(o[0]), f2bf(o[1]), f2bf(o[2]), f2bf(o[3]));
            ushort4 u1 = make_ushort4(f2bf(o[4]), f2bf(o[5]), f2bf(o[6]), f2bf(o[7]));
            unsigned short* hbp = hb + (size_t)n*DD + c;
            *(ushort4*)hbp       = u0;
            *(ushort4*)(hbp + 4) = u1;
        }
    }
#undef EDGE_PROC
}

// ---------------- bond head v2: MFMA, wave = 16 edges ---------------------------------
__global__ __launch_bounds__(256)
void k_bond(const unsigned short* __restrict__ hb,
            const int* __restrict__ srcv, const int* __restrict__ dstv,
            const unsigned short* __restrict__ Wbt, const float* __restrict__ bb,
            float* __restrict__ out) {
    int lane = threadIdx.x & 63;
    int wave = threadIdx.x >> 6;
    int ebase = blockIdx.x*64 + wave*16;     // NE = 200000 = 3125*64 exact
    int l15 = lane & 15, l4 = lane >> 4;
    int e = ebase + l15;
    const unsigned short* hs = hb + (size_t)srcv[e]*DD;
    const unsigned short* hd = hb + (size_t)dstv[e]*DD;

    bf16x8 bfr[8];
    #pragma unroll
    for (int s = 0; s < 8; ++s)
        bfr[s] = *(const bf16x8*)(Wbt + l15*256 + s*32 + l4*8);

    float bbv = bb[l15];
    f32x4 acc = (f32x4){bbv, bbv, bbv, bbv};
    #pragma unroll
    for (int s = 0; s < 4; ++s) {
        bf16x8 af = *(const bf16x8*)(hs + s*32 + l4*8);
        acc = __builtin_amdgcn_mfma_f32_16x16x32_bf16(af, bfr[s], acc, 0, 0, 0);
    }
    #pragma unroll
    for (int s = 0; s < 4; ++s) {
        bf16x8 af = *(const bf16x8*)(hd + s*32 + l4*8);
        acc = __builtin_amdgcn_mfma_f32_16x16x32_bf16(af, bfr[4+s], acc, 0, 0, 0);
    }
    #pragma unroll
    for (int r = 0; r < 4; ++r)
        out[(size_t)(ebase + l4*4 + r)*16 + l15] = acc[r];
}

// ---------------- host ----------------
extern "C" void kernel_launch(void* const* d_in, const int* in_sizes, int n_in,
                              void* d_out, int out_size, void* d_ws, size_t ws_size,
                              hipStream_t stream) {
    const int*   x        = (const int*)d_in[0];
    const int*   edge_idx = (const int*)d_in[1];
    const int*   eattr    = (const int*)d_in[2];
    const float* atom_emb = (const float*)d_in[3];
    const float* bond_emb = (const float*)d_in[4];
    const float* Wl  = (const float*)d_in[5];
    const float* bl  = (const float*)d_in[6];
    const float* Wr  = (const float*)d_in[7];
    const float* br  = (const float*)d_in[8];
    const float* We  = (const float*)d_in[9];
    const float* att = (const float*)d_in[10];
    const float* bias= (const float*)d_in[11];
    const float* Wa  = (const float*)d_in[12];
    const float* ba  = (const float*)d_in[13];
    const float* Wb  = (const float*)d_in[14];
    const float* bb  = (const float*)d_in[15];

    const int* src = edge_idx;
    const int* dst = edge_idx + NE;

    char* p = (char*)d_ws;
    auto alloc = [&](size_t bytes) -> void* {
        void* r = p; p += (bytes + 255) & ~(size_t)255; return r;
    };
    float*          h      = (float*)alloc((size_t)NN*DD*4);
    unsigned short* hb     = (unsigned short*)alloc((size_t)NN*DD*2);
    unsigned short* xlr    = (unsigned short*)alloc((size_t)NN*1024*2);
    unsigned short* Wlrt   = (unsigned short*)alloc((size_t)NL*1024*DD*2);
    float*          blr    = (float*)alloc((size_t)NL*1024*4);
    unsigned short* Wat    = (unsigned short*)alloc((size_t)DD*VAv*2);
    unsigned short* Wbt    = (unsigned short*)alloc((size_t)16*256*2);
    __half*         eprojh = (__half*)alloc((size_t)NL*VBv*HC*2);
    int*            deg    = (int*)alloc((size_t)NN*4);
    int*            exc    = (int*)alloc((size_t)NN*4);
    int*            sums   = (int*)alloc(256*4);
    int*            rowptr = (int*)alloc((size_t)(NN+1)*4);
    int*            cnt    = (int*)alloc((size_t)NN*4);
    int*            packed = (int*)alloc((size_t)NE*4);

    float* atom_out = (float*)d_out;                      // [NN,128]
    float* bond_out = atom_out + (size_t)NN*VAv;          // [NE,16]

    hipMemsetAsync(deg, 0, (size_t)NN*4, stream);
    hipMemsetAsync(cnt, 0, (size_t)NN*4, stream);

    k_embed<<<7500, 256, 0, stream>>>(x, atom_emb, h, hb);
    k_convw<<<(NL*1024*DD + 255)/256, 256, 0, stream>>>(Wl, Wr, bl, br, Wlrt, blr);
    k_convwa<<<(DD*VAv + 255)/256, 256, 0, stream>>>(Wa, Wat);
    k_convwb<<<16, 256, 0, stream>>>(Wb, Wbt);
    k_eproj<<<(NL*VBv*HC + 255)/256, 256, 0, stream>>>(bond_emb, We, eprojh);

    // CSR by dst
    int nchunks = (NN + SCAN_CHUNK - 1) / SCAN_CHUNK;     // 118
    k_deg<<<(NE+255)/256, 256, 0, stream>>>(dst, deg);
    k_scan1<<<nchunks, SCAN_CHUNK, 0, stream>>>(deg, exc, sums);
    k_scan2<<<1, 128, 0, stream>>>(sums, nchunks);
    k_scan3<<<(NN+256)/256, 256, 0, stream>>>(exc, sums, rowptr);
    k_scatter<<<(NE+255)/256, 256, 0, stream>>>(src, dst, eattr, rowptr, cnt, packed);

    const int MTILES = (NN + 127) / 128;                  // 469
    const int GRP4 = (MTILES + 3) / 4;                    // 118 panels (MT=4)
    const int GRP2 = (MTILES + 1) / 2;                    // 235 panels (MT=2)
    const int SWZ_BLKS = ((GRP4 + 7) / 8) * 64;           // 960 (15 octets x 64)
    for (int l = 0; l < NL; ++l) {
        const float* att_l  = att  + (size_t)l*NH*VAv;
        const float* bias_l = bias + (size_t)l*DD;
        const unsigned short* Wlrt_l = Wlrt + (size_t)l*1024*DD;
        const float* blr_l = blr + (size_t)l*1024;
        const __half* ep_l = eprojh + (size_t)l*VBv*HC;

        k_gemm_mfma<2, 4, true><<<SWZ_BLKS, 512, 0, stream>>>(hb, Wlrt_l, blr_l, xlr, NN, 1024, GRP4);
        k_aggregate<<<2500, 512, 0, stream>>>(xlr, ep_l, rowptr, packed, att_l, bias_l, h, hb);
    }

    k_gemm_mfma<0, 2, false><<<dim3(VAv/128, GRP2), 512, 0, stream>>>(hb, Wat, ba, atom_out, NN, VAv, GRP2);
    k_bond<<<NE/64, 256, 0, stream>>>(hb, src, dst, Wbt, bb, bond_out);
}

// Round 16
// 392.111 us; speedup vs baseline: 1.0659x; 1.0081x over previous
//
#include <hip/hip_runtime.h>
#include <hip/hip_bf16.h>
#include <hip/hip_fp16.h>
#include <math.h>

#define NN 60000
#define NE 200000
#define DD 128
#define NH 4
#define HC 512   // NH * C
#define NL 3
#define VAv 128
#define VBv 16
#define SCAN_CHUNK 512

typedef __attribute__((ext_vector_type(8))) short bf16x8;
typedef __attribute__((ext_vector_type(4))) float f32x4;
typedef _Float16 h2 __attribute__((ext_vector_type(2)));
typedef __fp16 fp16x2 __attribute__((ext_vector_type(2)));

__device__ __forceinline__ float bf2f(unsigned short u){
    union{unsigned int i; float f;} v; v.i = ((unsigned int)u)<<16; return v.f;
}
__device__ __forceinline__ unsigned short f2bf(float f){
    union{float f; unsigned int i;} v; v.f = f;
    unsigned int r = v.i + 0x7fffu + ((v.i>>16)&1u);
    return (unsigned short)(r>>16);
}
__device__ __forceinline__ h2 as_h2(unsigned int u){
    union{unsigned int x; h2 h;} c; c.x = u; return c.h;
}
__device__ __forceinline__ unsigned int pkrtz_u(float a, float b){
    union{fp16x2 h; unsigned int x;} c; c.h = __builtin_amdgcn_cvt_pkrtz(a, b); return c.x;
}

#define GLOAD_LDS16(g, l) \
    __builtin_amdgcn_global_load_lds((const __attribute__((address_space(1))) void*)(g), \
                                     (__attribute__((address_space(3))) void*)(l), 16, 0, 0)

// ---------------- embedding gather: h[n,:] = atom_emb[x[n],:] (fp32 + bf16) ----------
__global__ void k_embed(const int* __restrict__ x, const float* __restrict__ atom_emb,
                        float* __restrict__ h, unsigned short* __restrict__ hb) {
    int idx = blockIdx.x*blockDim.x + threadIdx.x;   // float4 index
    if (idx >= NN*(DD/4)) return;
    int n = idx >> 5;
    int c4 = idx & 31;
    int a = x[n];
    float4 v = ((const float4*)(atom_emb + (size_t)a*DD))[c4];
    ((float4*)(h + (size_t)n*DD))[c4] = v;
    ushort4 u = make_ushort4(f2bf(v.x), f2bf(v.y), f2bf(v.z), f2bf(v.w));
    ((ushort4*)(hb + (size_t)n*DD))[c4] = u;
}

// -------- weight convert: [Wl|Wr] -> Wlrt[l][1024][128] bf16 transposed; blr ---------
__global__ void k_convw(const float* __restrict__ Wl, const float* __restrict__ Wr,
                        const float* __restrict__ bl, const float* __restrict__ br,
                        unsigned short* __restrict__ Wlrt, float* __restrict__ blr) {
    int t = blockIdx.x*256 + threadIdx.x;
    if (t < NL*1024*DD) {
        int l = t / (1024*DD);
        int r = t % (1024*DD);
        int n = r / DD;      // 0..1023
        int k = r % DD;
        float v = (n < HC) ? Wl[(size_t)l*DD*HC + (size_t)k*HC + n]
                           : Wr[(size_t)l*DD*HC + (size_t)k*HC + (n - HC)];
        Wlrt[t] = f2bf(v);
    }
    if (t < NL*1024) {
        int l = t / 1024, j = t % 1024;
        blr[t] = (j < HC) ? bl[(size_t)l*HC + j] : br[(size_t)l*HC + (j - HC)];
    }
}

// ---------------- Wa convert: fp32 [128][128] -> bf16 transposed ---------------------
__global__ void k_convwa(const float* __restrict__ Wa, unsigned short* __restrict__ Wat) {
    int t = blockIdx.x*256 + threadIdx.x;
    if (t >= DD*VAv) return;
    int n = t / DD;
    int k = t % DD;
    Wat[t] = f2bf(Wa[(size_t)k*VAv + n]);
}

// ---------------- Wb convert: fp32 [256][16] -> Wbt bf16 [16][256] -------------------
__global__ void k_convwb(const float* __restrict__ Wb, unsigned short* __restrict__ Wbt) {
    int t = blockIdx.x*256 + threadIdx.x;
    if (t >= 16*256) return;
    int c = t >> 8, k = t & 255;
    Wbt[t] = f2bf(Wb[(size_t)k*16 + c]);
}

// -------- eproj (all layers): f16 linear [l][v][n] -----------------------------------
__global__ void k_eproj(const float* __restrict__ bond_emb, const float* __restrict__ We,
                        __half* __restrict__ eprojh) {
    int t = blockIdx.x*256 + threadIdx.x;    // 24576 total
    if (t >= NL*VBv*HC) return;
    int n = t & (HC-1);
    int v = (t >> 9) & (VBv-1);
    int l = t >> 13;
    const float* be = bond_emb + (size_t)v*DD;         // wave-uniform -> scalar
    const float* w  = We + (size_t)l*DD*HC + n;
    float acc = 0.f;
    #pragma unroll 8
    for (int k = 0; k < DD; ++k) acc = fmaf(be[k], w[(size_t)k*HC], acc);
    eprojh[t] = __float2half(acc);
}

// ---------------- CSR build ----------------
__global__ void k_deg(const int* __restrict__ dst, int* __restrict__ deg) {
    int e = blockIdx.x*blockDim.x + threadIdx.x;
    if (e < NE) atomicAdd(&deg[dst[e]], 1);
}

__global__ void k_scan1(const int* __restrict__ deg, int* __restrict__ exc, int* __restrict__ sums) {
    __shared__ int buf[2][SCAN_CHUNK];
    int t = threadIdx.x;
    int gi = blockIdx.x*SCAN_CHUNK + t;
    int v = (gi < NN) ? deg[gi] : 0;
    buf[0][t] = v;
    __syncthreads();
    int cur = 0;
    for (int off = 1; off < SCAN_CHUNK; off <<= 1) {
        int nv = buf[cur][t] + ((t >= off) ? buf[cur][t-off] : 0);
        buf[cur^1][t] = nv;
        __syncthreads();
        cur ^= 1;
    }
    if (gi < NN) exc[gi] = buf[cur][t] - v;
    if (t == SCAN_CHUNK-1) sums[blockIdx.x] = buf[cur][t];
}

__global__ void k_scan2(int* sums, int nb) {     // nb <= 128
    __shared__ int buf[2][128];
    int t = threadIdx.x;
    int v = (t < nb) ? sums[t] : 0;
    buf[0][t] = v;
    __syncthreads();
    int cur = 0;
    for (int off = 1; off < 128; off <<= 1) {
        int nv = buf[cur][t] + ((t >= off) ? buf[cur][t-off] : 0);
        buf[cur^1][t] = nv;
        __syncthreads();
        cur ^= 1;
    }
    if (t < nb) sums[t] = buf[cur][t] - v;       // exclusive
}

__global__ void k_scan3(const int* __restrict__ exc, const int* __restrict__ sums,
                        int* __restrict__ rowptr) {
    int i = blockIdx.x*blockDim.x + threadIdx.x;
    if (i < NN) rowptr[i] = exc[i] + sums[i / SCAN_CHUNK];
    if (i == NN) rowptr[NN] = NE;
}

// scatter: store src | (eattr<<16) sorted by dst  (src < 65536, eattr < 16)
__global__ void k_scatter(const int* __restrict__ srcv, const int* __restrict__ dst,
                          const int* __restrict__ eattr, const int* __restrict__ rowptr,
                          int* __restrict__ cnt, int* __restrict__ packed) {
    int e = blockIdx.x*blockDim.x + threadIdx.x;
    if (e < NE) {
        int d = dst[e];
        int pos = atomicAdd(&cnt[d], 1);
        packed[rowptr[d] + pos] = srcv[e] | (eattr[e] << 16);
    }
}

// ------- MFMA bf16 GEMM v6: 8-wave blocks (64x32 wave-tile), deep MT pipeline --------
template<int OM, int MT, bool SWZ>
__global__ __launch_bounds__(512)
void k_gemm_mfma(const unsigned short* __restrict__ A,
                 const unsigned short* __restrict__ Bt,
                 const float* __restrict__ bias, void* __restrict__ Cout,
                 int M, int Nc, int NP) {
    __shared__ unsigned short As[2][128*128];      // 64 KB
    const int tid = threadIdx.x;
    const int lane = tid & 63;
    const int wave = tid >> 6;                     // 0..7

    int bn, bm0;
    if (SWZ) {
        int F = blockIdx.x;
        int P = (F & 7) + ((F >> 6) << 3);
        if (P >= NP) return;
        bn  = ((F >> 3) & 7) * 128;
        bm0 = P * (128*MT);
    } else {
        bn  = blockIdx.x * 128;
        bm0 = blockIdx.y * (128*MT);
    }

    const int l15 = lane & 15;
    const int l4  = lane >> 4;
    const int wm = (wave >> 2) * 64;               // 0 or 64
    const int wn = (wave & 3) * 32;                // 0,32,64,96

    // B fragments once (L2-hot), reused across all MT tiles
    bf16x8 bfr[4][2];
    #pragma unroll
    for (int ks = 0; ks < 4; ++ks)
        #pragma unroll
        for (int ni = 0; ni < 2; ++ni)
            bfr[ks][ni] = *(const bf16x8*)(Bt + (size_t)(bn + wn + ni*16 + l15)*128
                                              + (size_t)(ks*4 + l4)*8);

    float4 bv[2];
    #pragma unroll
    for (int ni = 0; ni < 2; ++ni)
        bv[ni] = bias ? *(const float4*)(bias + bn + wn + ni*16 + l4*4)
                      : make_float4(0.f, 0.f, 0.f, 0.f);

    auto stage = [&](int buf, int bm) {
        #pragma unroll
        for (int it = 0; it < 4; ++it) {
            int slot = it*512 + tid;        // 16B-chunk slot, 2048 per tile
            int row  = slot >> 4;
            int cph  = slot & 15;
            int clog = cph ^ (row & 15);
            int arow = bm + row; if (arow >= M) arow = M - 1;
            unsigned short* ldst = &As[buf][(size_t)(it*512 + (tid & ~63))*8];
            GLOAD_LDS16(A + (size_t)arow*128 + clog*8, ldst);
        }
    };

    stage(0, bm0);
    asm volatile("s_waitcnt vmcnt(0)" ::: "memory");
    __syncthreads();

    int cur = 0;
    for (int t = 0; t < MT; ++t) {
        int bm = bm0 + t*128;
        if (bm >= M) break;
        bool pf = (t+1 < MT) && (bm + 128 < M);
        if (pf) stage(cur^1, bm + 128);            // 4 DMA loads in flight

        f32x4 acc[4][2];
        #pragma unroll
        for (int i = 0; i < 4; ++i)
            #pragma unroll
            for (int j = 0; j < 2; ++j)
                acc[i][j] = (f32x4){0.f, 0.f, 0.f, 0.f};

        #pragma unroll
        for (int ks = 0; ks < 4; ++ks) {
            bf16x8 af[4];
            int cph = (ks*4 + l4) ^ l15;           // row&15 == l15 for fragment rows
            #pragma unroll
            for (int mi = 0; mi < 4; ++mi) {
                int row = wm + mi*16 + l15;
                af[mi] = *(const bf16x8*)(&As[cur][(size_t)row*128 + cph*8]);
            }
            #pragma unroll
            for (int mi = 0; mi < 4; ++mi)
                #pragma unroll
                for (int ni = 0; ni < 2; ++ni)
                    acc[mi][ni] = __builtin_amdgcn_mfma_f32_16x16x32_bf16(bfr[ks][ni], af[mi], acc[mi][ni], 0, 0, 0);
        }

        // epilogue: row = bm+wm+mi*16+l15; cols = bn+wn+ni*16+l4*4 .. +3  (8 stores)
        #pragma unroll
        for (int mi = 0; mi < 4; ++mi) {
            int row = bm + wm + mi*16 + l15;
            bool rok = (row < M);
            #pragma unroll
            for (int ni = 0; ni < 2; ++ni) {
                float v0 = acc[mi][ni][0] + bv[ni].x;
                float v1 = acc[mi][ni][1] + bv[ni].y;
                float v2 = acc[mi][ni][2] + bv[ni].z;
                float v3 = acc[mi][ni][3] + bv[ni].w;
                int colb = bn + wn + ni*16 + l4*4;
                if (rok) {
                    if (OM == 2) {
                        *(uint2*)((unsigned short*)Cout + (size_t)row*Nc + colb)
                            = make_uint2(pkrtz_u(v0, v1), pkrtz_u(v2, v3));
                    } else {
                        *(float4*)((float*)Cout + (size_t)row*Nc + colb) = make_float4(v0, v1, v2, v3);
                    }
                }
            }
        }

        if (pf) {
            // newest 8 vmem ops are this tile's stores; ensures the 4 DMAs landed
            asm volatile("s_waitcnt vmcnt(8)" ::: "memory");
            __builtin_amdgcn_s_barrier();          // all waves done reading As[cur]
        }
        cur ^= 1;
    }
}

// ---- fused edge-logits + softmax + aggregate + epilogue (packed f16 math) ----------
// 8 waves/block, one node per wave, grid-stride. Lane l: channels l*8..+8 (f16).
// xlr row: [xl 512 | xr 512] f16. eps: 16KB LDS, 1KB/row, lane-stride-16B b128 reads.
__global__ __launch_bounds__(512)
void k_aggregate(const unsigned short* __restrict__ xlr,
                 const __half* __restrict__ eprojh,  // [16][512] f16, this layer
                 const int* __restrict__ rowptr, const int* __restrict__ packed,
                 const float* __restrict__ att,      // [4][128], this layer
                 const float* __restrict__ bias,     // [128], this layer
                 float* __restrict__ h, unsigned short* __restrict__ hb) {
    __shared__ uint4 eps4[1024];                     // 16 KB
    {
        const uint4* s4 = (const uint4*)eprojh;
        int t = threadIdx.x;
        eps4[t]       = s4[t];
        eps4[t + 512] = s4[t + 512];
    }
    __syncthreads();

    const int wave = threadIdx.x >> 6;
    const int lane = threadIdx.x & 63;
    const int loff = lane*8;                         // ushort index into row
    const h2 k02 = {(_Float16)0.2f, (_Float16)0.2f};

    h2 attf[4];
    {
        float4 a0 = *(const float4*)(att + loff);
        float4 a1 = *(const float4*)(att + loff + 4);
        attf[0] = (h2){(_Float16)a0.x, (_Float16)a0.y};
        attf[1] = (h2){(_Float16)a0.z, (_Float16)a0.w};
        attf[2] = (h2){(_Float16)a1.x, (_Float16)a1.y};
        attf[3] = (h2){(_Float16)a1.z, (_Float16)a1.w};
    }

#define EDGE_PROC(xr_, er_) do {                                            \
        h2 x0 = as_h2(xr_.x), x1 = as_h2(xr_.y);                            \
        h2 x2 = as_h2(xr_.z), x3 = as_h2(xr_.w);                            \
        h2 z0 = x0 + xrf[0] + as_h2(er_.x);                                 \
        h2 z1 = x1 + xrf[1] + as_h2(er_.y);                                 \
        h2 z2 = x2 + xrf[2] + as_h2(er_.z);                                 \
        h2 z3 = x3 + xrf[3] + as_h2(er_.w);                                 \
        h2 lacc = __builtin_elementwise_max(z0, z0*k02) * attf[0];          \
        lacc += __builtin_elementwise_max(z1, z1*k02) * attf[1];            \
        lacc += __builtin_elementwise_max(z2, z2*k02) * attf[2];            \
        lacc += __builtin_elementwise_max(z3, z3*k02) * attf[3];            \
        float pz_ = (float)lacc[0] + (float)lacc[1];                        \
        pz_ += __shfl_xor(pz_, 1);                                          \
        pz_ += __shfl_xor(pz_, 2);                                          \
        pz_ += __shfl_xor(pz_, 4);                                          \
        pz_ += __shfl_xor(pz_, 8);                                          \
        float w_ = __expf(pz_);                                             \
        wsum += w_;                                                         \
        h2 wh = {(_Float16)w_, (_Float16)w_};                               \
        acc0 += wh*x0; acc1 += wh*x1; acc2 += wh*x2; acc3 += wh*x3;         \
    } while (0)

    for (int g = blockIdx.x; g < NN/8; g += gridDim.x) {
        int n = g*8 + wave;

        h2 xrf[4];
        {
            uint4 raw = *(const uint4*)(xlr + (size_t)n*1024 + 512 + loff);
            xrf[0] = as_h2(raw.x); xrf[1] = as_h2(raw.y);
            xrf[2] = as_h2(raw.z); xrf[3] = as_h2(raw.w);
        }

        h2 acc0 = {0,0}, acc1 = {0,0}, acc2 = {0,0}, acc3 = {0,0};
        float wsum = 0.f;
        int beg = rowptr[n], end = rowptr[n+1];
        int p = beg;

        for (; p + 4 <= end; p += 4) {               // 4 edges in flight
            int pk0 = packed[p],   pk1 = packed[p+1];
            int pk2 = packed[p+2], pk3 = packed[p+3];
            uint4 v0 = *(const uint4*)(xlr + (size_t)(pk0 & 0xFFFF)*1024 + loff);
            uint4 v1 = *(const uint4*)(xlr + (size_t)(pk1 & 0xFFFF)*1024 + loff);
            uint4 v2 = *(const uint4*)(xlr + (size_t)(pk2 & 0xFFFF)*1024 + loff);
            uint4 v3 = *(const uint4*)(xlr + (size_t)(pk3 & 0xFFFF)*1024 + loff);
            uint4 e0 = eps4[(pk0 >> 16)*64 + lane];
            uint4 e1 = eps4[(pk1 >> 16)*64 + lane];
            uint4 e2 = eps4[(pk2 >> 16)*64 + lane];
            uint4 e3 = eps4[(pk3 >> 16)*64 + lane];
            EDGE_PROC(v0, e0);
            EDGE_PROC(v1, e1);
            EDGE_PROC(v2, e2);
            EDGE_PROC(v3, e3);
        }
        if (p + 2 <= end) {                          // 2-wide tail
            int pk0 = packed[p], pk1 = packed[p+1];
            uint4 v0 = *(const uint4*)(xlr + (size_t)(pk0 & 0xFFFF)*1024 + loff);
            uint4 v1 = *(const uint4*)(xlr + (size_t)(pk1 & 0xFFFF)*1024 + loff);
            uint4 e0 = eps4[(pk0 >> 16)*64 + lane];
            uint4 e1 = eps4[(pk1 >> 16)*64 + lane];
            EDGE_PROC(v0, e0);
            EDGE_PROC(v1, e1);
            p += 2;
        }
        if (p < end) {                               // 1-wide tail
            int pk0 = packed[p];
            uint4 v0 = *(const uint4*)(xlr + (size_t)(pk0 & 0xFFFF)*1024 + loff);
            uint4 e0 = eps4[(pk0 >> 16)*64 + lane];
            EDGE_PROC(v0, e0);
        }

        float inv = __builtin_amdgcn_rcpf(wsum + 1e-16f);
        float rr[8];
        rr[0] = (float)acc0[0]; rr[1] = (float)acc0[1];
        rr[2] = (float)acc1[0]; rr[3] = (float)acc1[1];
        rr[4] = (float)acc2[0]; rr[5] = (float)acc2[1];
        rr[6] = (float)acc3[0]; rr[7] = (float)acc3[1];
        #pragma unroll
        for (int u = 0; u < 8; ++u) rr[u] *= inv;
        #pragma unroll
        for (int u = 0; u < 8; ++u) rr[u] += __shfl_xor(rr[u], 16);
        #pragma unroll
        for (int u = 0; u < 8; ++u) rr[u] += __shfl_xor(rr[u], 32);

        if (lane < 16) {
            int c = lane*8;
            float* hp = h + (size_t)n*DD + c;
            float4 h0 = *(const float4*)hp;
            float4 h1 = *(const float4*)(hp + 4);
            float4 b0 = *(const float4*)(bias + c);
            float4 b1 = *(const float4*)(bias + c + 4);
            float o[8];
            o[0] = h0.x + fmaxf(0.f, fmaf(0.25f, rr[0], b0.x));
            o[1] = h0.y + fmaxf(0.f, fmaf(0.25f, rr[1], b0.y));
            o[2] = h0.z + fmaxf(0.f, fmaf(0.25f, rr[2], b0.z));
            o[3] = h0.w + fmaxf(0.f, fmaf(0.25f, rr[3], b0.w));
            o[4] = h1.x + fmaxf(0.f, fmaf(0.25f, rr[4], b1.x));
            o[5] = h1.y + fmaxf(0.f, fmaf(0.25f, rr[5], b1.y));
            o[6] = h1.z + fmaxf(0.f, fmaf(0.25f, rr[6], b1.z));
            o[7] = h1.w + fmaxf(0.f, fmaf(0.25f, rr[7], b1.w));
            *(float4*)hp       = make_float4(o[0], o[1], o[2], o[3]);
            *(float4*)(hp + 4) = make_float4(o[4], o[5], o[6], o[7]);
            ushort4 u0 = make_ushort4(f2bf(o[0]), f2bf(o[1]), f2bf(o[2]), f2bf(o[3]));
            ushort4 u1 = make_ushort4(f2bf(o[4]), f2bf(o[5]), f2bf(o[6]), f2bf(o[7]));
            unsigned short* hbp = hb + (size_t)n*DD + c;
            *(ushort4*)hbp       = u0;
            *(ushort4*)(hbp + 4) = u1;
        }
    }
#undef EDGE_PROC
}

// ---------------- bond head v2: MFMA, wave = 16 edges ---------------------------------
__global__ __launch_bounds__(256)
void k_bond(const unsigned short* __restrict__ hb,
            const int* __restrict__ srcv, const int* __restrict__ dstv,
            const unsigned short* __restrict__ Wbt, const float* __restrict__ bb,
            float* __restrict__ out) {
    int lane = threadIdx.x & 63;
    int wave = threadIdx.x >> 6;
    int ebase = blockIdx.x*64 + wave*16;     // NE = 200000 = 3125*64 exact
    int l15 = lane & 15, l4 = lane >> 4;
    int e = ebase + l15;
    const unsigned short* hs = hb + (size_t)srcv[e]*DD;
    const unsigned short* hd = hb + (size_t)dstv[e]*DD;

    bf16x8 bfr[8];
    #pragma unroll
    for (int s = 0; s < 8; ++s)
        bfr[s] = *(const bf16x8*)(Wbt + l15*256 + s*32 + l4*8);

    float bbv = bb[l15];
    f32x4 acc = (f32x4){bbv, bbv, bbv, bbv};
    #pragma unroll
    for (int s = 0; s < 4; ++s) {
        bf16x8 af = *(const bf16x8*)(hs + s*32 + l4*8);
        acc = __builtin_amdgcn_mfma_f32_16x16x32_bf16(af, bfr[s], acc, 0, 0, 0);
    }
    #pragma unroll
    for (int s = 0; s < 4; ++s) {
        bf16x8 af = *(const bf16x8*)(hd + s*32 + l4*8);
        acc = __builtin_amdgcn_mfma_f32_16x16x32_bf16(af, bfr[4+s], acc, 0, 0, 0);
    }
    #pragma unroll
    for (int r = 0; r < 4; ++r)
        out[(size_t)(ebase + l4*4 + r)*16 + l15] = acc[r];
}

// ---------------- host ----------------
extern "C" void kernel_launch(void* const* d_in, const int* in_sizes, int n_in,
                              void* d_out, int out_size, void* d_ws, size_t ws_size,
                              hipStream_t stream) {
    const int*   x        = (const int*)d_in[0];
    const int*   edge_idx = (const int*)d_in[1];
    const int*   eattr    = (const int*)d_in[2];
    const float* atom_emb = (const float*)d_in[3];
    const float* bond_emb = (const float*)d_in[4];
    const float* Wl  = (const float*)d_in[5];
    const float* bl  = (const float*)d_in[6];
    const float* Wr  = (const float*)d_in[7];
    const float* br  = (const float*)d_in[8];
    const float* We  = (const float*)d_in[9];
    const float* att = (const float*)d_in[10];
    const float* bias= (const float*)d_in[11];
    const float* Wa  = (const float*)d_in[12];
    const float* ba  = (const float*)d_in[13];
    const float* Wb  = (const float*)d_in[14];
    const float* bb  = (const float*)d_in[15];

    const int* src = edge_idx;
    const int* dst = edge_idx + NE;

    char* p = (char*)d_ws;
    auto alloc = [&](size_t bytes) -> void* {
        void* r = p; p += (bytes + 255) & ~(size_t)255; return r;
    };
    float*          h      = (float*)alloc((size_t)NN*DD*4);
    unsigned short* hb     = (unsigned short*)alloc((size_t)NN*DD*2);
    unsigned short* xlr    = (unsigned short*)alloc((size_t)NN*1024*2);
    unsigned short* Wlrt   = (unsigned short*)alloc((size_t)NL*1024*DD*2);
    float*          blr    = (float*)alloc((size_t)NL*1024*4);
    unsigned short* Wat    = (unsigned short*)alloc((size_t)DD*VAv*2);
    unsigned short* Wbt    = (unsigned short*)alloc((size_t)16*256*2);
    __half*         eprojh = (__half*)alloc((size_t)NL*VBv*HC*2);
    int*            deg    = (int*)alloc((size_t)NN*4);
    int*            exc    = (int*)alloc((size_t)NN*4);
    int*            sums   = (int*)alloc(256*4);
    int*            rowptr = (int*)alloc((size_t)(NN+1)*4);
    int*            cnt    = (int*)alloc((size_t)NN*4);
    int*            packed = (int*)alloc((size_t)NE*4);

    float* atom_out = (float*)d_out;                      // [NN,128]
    float* bond_out = atom_out + (size_t)NN*VAv;          // [NE,16]

    hipMemsetAsync(deg, 0, (size_t)NN*4, stream);
    hipMemsetAsync(cnt, 0, (size_t)NN*4, stream);

    k_embed<<<7500, 256, 0, stream>>>(x, atom_emb, h, hb);
    k_convw<<<(NL*1024*DD + 255)/256, 256, 0, stream>>>(Wl, Wr, bl, br, Wlrt, blr);
    k_convwa<<<(DD*VAv + 255)/256, 256, 0, stream>>>(Wa, Wat);
    k_convwb<<<16, 256, 0, stream>>>(Wb, Wbt);
    k_eproj<<<(NL*VBv*HC + 255)/256, 256, 0, stream>>>(bond_emb, We, eprojh);

    // CSR by dst
    int nchunks = (NN + SCAN_CHUNK - 1) / SCAN_CHUNK;     // 118
    k_deg<<<(NE+255)/256, 256, 0, stream>>>(dst, deg);
    k_scan1<<<nchunks, SCAN_CHUNK, 0, stream>>>(deg, exc, sums);
    k_scan2<<<1, 128, 0, stream>>>(sums, nchunks);
    k_scan3<<<(NN+256)/256, 256, 0, stream>>>(exc, sums, rowptr);
    k_scatter<<<(NE+255)/256, 256, 0, stream>>>(src, dst, eattr, rowptr, cnt, packed);

    const int MTILES = (NN + 127) / 128;                  // 469
    const int GRP8 = (MTILES + 7) / 8;                    // 59 panels (MT=8)
    const int GRP4 = (MTILES + 3) / 4;                    // 118 panels (MT=4, Wa)
    const int SWZ_BLKS = ((GRP8 + 7) / 8) * 64;           // 512 (8 octets x 64)
    for (int l = 0; l < NL; ++l) {
        const float* att_l  = att  + (size_t)l*NH*VAv;
        const float* bias_l = bias + (size_t)l*DD;
        const unsigned short* Wlrt_l = Wlrt + (size_t)l*1024*DD;
        const float* blr_l = blr + (size_t)l*1024;
        const __half* ep_l = eprojh + (size_t)l*VBv*HC;

        k_gemm_mfma<2, 8, true><<<SWZ_BLKS, 512, 0, stream>>>(hb, Wlrt_l, blr_l, xlr, NN, 1024, GRP8);
        k_aggregate<<<2500, 512, 0, stream>>>(xlr, ep_l, rowptr, packed, att_l, bias_l, h, hb);
    }

    k_gemm_mfma<0, 4, false><<<dim3(VAv/128, GRP4), 512, 0, stream>>>(hb, Wat, ba, atom_out, NN, VAv, GRP4);
    k_bond<<<NE/64, 256, 0, stream>>>(hb, src, dst, Wbt, bb, bond_out);
}

// Round 17
// 380.808 us; speedup vs baseline: 1.0976x; 1.0297x over previous
//
#include <hip/hip_runtime.h>
#include <hip/hip_bf16.h>
#include <hip/hip_fp16.h>
#include <math.h>

#define NN 60000
#define NE 200000
#define DD 128
#define NH 4
#define HC 512   // NH * C
#define NL 3
#define VAv 128
#define VBv 16
#define SCAN_CHUNK 512

typedef __attribute__((ext_vector_type(8))) short bf16x8;
typedef __attribute__((ext_vector_type(4))) float f32x4;
typedef _Float16 h2 __attribute__((ext_vector_type(2)));
typedef __fp16 fp16x2 __attribute__((ext_vector_type(2)));

__device__ __forceinline__ float bf2f(unsigned short u){
    union{unsigned int i; float f;} v; v.i = ((unsigned int)u)<<16; return v.f;
}
__device__ __forceinline__ unsigned short f2bf(float f){
    union{float f; unsigned int i;} v; v.f = f;
    unsigned int r = v.i + 0x7fffu + ((v.i>>16)&1u);
    return (unsigned short)(r>>16);
}
__device__ __forceinline__ h2 as_h2(unsigned int u){
    union{unsigned int x; h2 h;} c; c.x = u; return c.h;
}
__device__ __forceinline__ unsigned int pkrtz_u(float a, float b){
    union{fp16x2 h; unsigned int x;} c; c.h = __builtin_amdgcn_cvt_pkrtz(a, b); return c.x;
}

#define GLOAD_LDS16(g, l) \
    __builtin_amdgcn_global_load_lds((const __attribute__((address_space(1))) void*)(g), \
                                     (__attribute__((address_space(3))) void*)(l), 16, 0, 0)

// ---------------- embedding gather: hb[n,:] = bf16(atom_emb[x[n],:]) -----------------
__global__ void k_embed(const int* __restrict__ x, const float* __restrict__ atom_emb,
                        unsigned short* __restrict__ hb) {
    int idx = blockIdx.x*blockDim.x + threadIdx.x;   // float4 index
    if (idx >= NN*(DD/4)) return;
    int n = idx >> 5;
    int c4 = idx & 31;
    int a = x[n];
    float4 v = ((const float4*)(atom_emb + (size_t)a*DD))[c4];
    ushort4 u = make_ushort4(f2bf(v.x), f2bf(v.y), f2bf(v.z), f2bf(v.w));
    ((ushort4*)(hb + (size_t)n*DD))[c4] = u;
}

// -------- weight convert: [Wl|Wr] -> Wlrt[l][1024][128] bf16 transposed; blr ---------
__global__ void k_convw(const float* __restrict__ Wl, const float* __restrict__ Wr,
                        const float* __restrict__ bl, const float* __restrict__ br,
                        unsigned short* __restrict__ Wlrt, float* __restrict__ blr) {
    int t = blockIdx.x*256 + threadIdx.x;
    if (t < NL*1024*DD) {
        int l = t / (1024*DD);
        int r = t % (1024*DD);
        int n = r / DD;      // 0..1023
        int k = r % DD;
        float v = (n < HC) ? Wl[(size_t)l*DD*HC + (size_t)k*HC + n]
                           : Wr[(size_t)l*DD*HC + (size_t)k*HC + (n - HC)];
        Wlrt[t] = f2bf(v);
    }
    if (t < NL*1024) {
        int l = t / 1024, j = t % 1024;
        blr[t] = (j < HC) ? bl[(size_t)l*HC + j] : br[(size_t)l*HC + (j - HC)];
    }
}

// ---------------- Wa convert: fp32 [128][128] -> bf16 transposed ---------------------
__global__ void k_convwa(const float* __restrict__ Wa, unsigned short* __restrict__ Wat) {
    int t = blockIdx.x*256 + threadIdx.x;
    if (t >= DD*VAv) return;
    int n = t / DD;
    int k = t % DD;
    Wat[t] = f2bf(Wa[(size_t)k*VAv + n]);
}

// ---------------- Wb convert: fp32 [256][16] -> Wbt bf16 [16][256] -------------------
__global__ void k_convwb(const float* __restrict__ Wb, unsigned short* __restrict__ Wbt) {
    int t = blockIdx.x*256 + threadIdx.x;
    if (t >= 16*256) return;
    int c = t >> 8, k = t & 255;
    Wbt[t] = f2bf(Wb[(size_t)k*16 + c]);
}

// -------- eproj (all layers): f16 linear [l][v][n] -----------------------------------
__global__ void k_eproj(const float* __restrict__ bond_emb, const float* __restrict__ We,
                        __half* __restrict__ eprojh) {
    int t = blockIdx.x*256 + threadIdx.x;    // 24576 total
    if (t >= NL*VBv*HC) return;
    int n = t & (HC-1);
    int v = (t >> 9) & (VBv-1);
    int l = t >> 13;
    const float* be = bond_emb + (size_t)v*DD;         // wave-uniform -> scalar
    const float* w  = We + (size_t)l*DD*HC + n;
    float acc = 0.f;
    #pragma unroll 8
    for (int k = 0; k < DD; ++k) acc = fmaf(be[k], w[(size_t)k*HC], acc);
    eprojh[t] = __float2half(acc);
}

// ---------------- CSR build ----------------
__global__ void k_deg(const int* __restrict__ dst, int* __restrict__ deg) {
    int e = blockIdx.x*blockDim.x + threadIdx.x;
    if (e < NE) atomicAdd(&deg[dst[e]], 1);
}

__global__ void k_scan1(const int* __restrict__ deg, int* __restrict__ exc, int* __restrict__ sums) {
    __shared__ int buf[2][SCAN_CHUNK];
    int t = threadIdx.x;
    int gi = blockIdx.x*SCAN_CHUNK + t;
    int v = (gi < NN) ? deg[gi] : 0;
    buf[0][t] = v;
    __syncthreads();
    int cur = 0;
    for (int off = 1; off < SCAN_CHUNK; off <<= 1) {
        int nv = buf[cur][t] + ((t >= off) ? buf[cur][t-off] : 0);
        buf[cur^1][t] = nv;
        __syncthreads();
        cur ^= 1;
    }
    if (gi < NN) exc[gi] = buf[cur][t] - v;
    if (t == SCAN_CHUNK-1) sums[blockIdx.x] = buf[cur][t];
}

__global__ void k_scan2(int* sums, int nb) {     // nb <= 128
    __shared__ int buf[2][128];
    int t = threadIdx.x;
    int v = (t < nb) ? sums[t] : 0;
    buf[0][t] = v;
    __syncthreads();
    int cur = 0;
    for (int off = 1; off < 128; off <<= 1) {
        int nv = buf[cur][t] + ((t >= off) ? buf[cur][t-off] : 0);
        buf[cur^1][t] = nv;
        __syncthreads();
        cur ^= 1;
    }
    if (t < nb) sums[t] = buf[cur][t] - v;       // exclusive
}

__global__ void k_scan3(const int* __restrict__ exc, const int* __restrict__ sums,
                        int* __restrict__ rowptr) {
    int i = blockIdx.x*blockDim.x + threadIdx.x;
    if (i < NN) rowptr[i] = exc[i] + sums[i / SCAN_CHUNK];
    if (i == NN) rowptr[NN] = NE;
}

// scatter: store src | (eattr<<16) sorted by dst  (src < 65536, eattr < 16)
__global__ void k_scatter(const int* __restrict__ srcv, const int* __restrict__ dst,
                          const int* __restrict__ eattr, const int* __restrict__ rowptr,
                          int* __restrict__ cnt, int* __restrict__ packed) {
    int e = blockIdx.x*blockDim.x + threadIdx.x;
    if (e < NE) {
        int d = dst[e];
        int pos = atomicAdd(&cnt[d], 1);
        packed[rowptr[d] + pos] = srcv[e] | (eattr[e] << 16);
    }
}

// ------- MFMA bf16 GEMM v6: 8-wave blocks (64x32 wave-tile), deep MT pipeline --------
template<int OM, int MT, bool SWZ>
__global__ __launch_bounds__(512)
void k_gemm_mfma(const unsigned short* __restrict__ A,
                 const unsigned short* __restrict__ Bt,
                 const float* __restrict__ bias, void* __restrict__ Cout,
                 int M, int Nc, int NP) {
    __shared__ unsigned short As[2][128*128];      // 64 KB
    const int tid = threadIdx.x;
    const int lane = tid & 63;
    const int wave = tid >> 6;                     // 0..7

    int bn, bm0;
    if (SWZ) {
        int F = blockIdx.x;
        int P = (F & 7) + ((F >> 6) << 3);
        if (P >= NP) return;
        bn  = ((F >> 3) & 7) * 128;
        bm0 = P * (128*MT);
    } else {
        bn  = blockIdx.x * 128;
        bm0 = blockIdx.y * (128*MT);
    }

    const int l15 = lane & 15;
    const int l4  = lane >> 4;
    const int wm = (wave >> 2) * 64;               // 0 or 64
    const int wn = (wave & 3) * 32;                // 0,32,64,96

    // B fragments once (L2-hot), reused across all MT tiles
    bf16x8 bfr[4][2];
    #pragma unroll
    for (int ks = 0; ks < 4; ++ks)
        #pragma unroll
        for (int ni = 0; ni < 2; ++ni)
            bfr[ks][ni] = *(const bf16x8*)(Bt + (size_t)(bn + wn + ni*16 + l15)*128
                                              + (size_t)(ks*4 + l4)*8);

    float4 bv[2];
    #pragma unroll
    for (int ni = 0; ni < 2; ++ni)
        bv[ni] = bias ? *(const float4*)(bias + bn + wn + ni*16 + l4*4)
                      : make_float4(0.f, 0.f, 0.f, 0.f);

    auto stage = [&](int buf, int bm) {
        #pragma unroll
        for (int it = 0; it < 4; ++it) {
            int slot = it*512 + tid;        // 16B-chunk slot, 2048 per tile
            int row  = slot >> 4;
            int cph  = slot & 15;
            int clog = cph ^ (row & 15);
            int arow = bm + row; if (arow >= M) arow = M - 1;
            unsigned short* ldst = &As[buf][(size_t)(it*512 + (tid & ~63))*8];
            GLOAD_LDS16(A + (size_t)arow*128 + clog*8, ldst);
        }
    };

    stage(0, bm0);
    asm volatile("s_waitcnt vmcnt(0)" ::: "memory");
    __syncthreads();

    int cur = 0;
    for (int t = 0; t < MT; ++t) {
        int bm = bm0 + t*128;
        if (bm >= M) break;
        bool pf = (t+1 < MT) && (bm + 128 < M);
        if (pf) stage(cur^1, bm + 128);            // 4 DMA loads in flight

        f32x4 acc[4][2];
        #pragma unroll
        for (int i = 0; i < 4; ++i)
            #pragma unroll
            for (int j = 0; j < 2; ++j)
                acc[i][j] = (f32x4){0.f, 0.f, 0.f, 0.f};

        #pragma unroll
        for (int ks = 0; ks < 4; ++ks) {
            bf16x8 af[4];
            int cph = (ks*4 + l4) ^ l15;           // row&15 == l15 for fragment rows
            #pragma unroll
            for (int mi = 0; mi < 4; ++mi) {
                int row = wm + mi*16 + l15;
                af[mi] = *(const bf16x8*)(&As[cur][(size_t)row*128 + cph*8]);
            }
            #pragma unroll
            for (int mi = 0; mi < 4; ++mi)
                #pragma unroll
                for (int ni = 0; ni < 2; ++ni)
                    acc[mi][ni] = __builtin_amdgcn_mfma_f32_16x16x32_bf16(bfr[ks][ni], af[mi], acc[mi][ni], 0, 0, 0);
        }

        // epilogue: row = bm+wm+mi*16+l15; cols = bn+wn+ni*16+l4*4 .. +3  (8 stores)
        #pragma unroll
        for (int mi = 0; mi < 4; ++mi) {
            int row = bm + wm + mi*16 + l15;
            bool rok = (row < M);
            #pragma unroll
            for (int ni = 0; ni < 2; ++ni) {
                float v0 = acc[mi][ni][0] + bv[ni].x;
                float v1 = acc[mi][ni][1] + bv[ni].y;
                float v2 = acc[mi][ni][2] + bv[ni].z;
                float v3 = acc[mi][ni][3] + bv[ni].w;
                int colb = bn + wn + ni*16 + l4*4;
                if (rok) {
                    if (OM == 2) {
                        *(uint2*)((unsigned short*)Cout + (size_t)row*Nc + colb)
                            = make_uint2(pkrtz_u(v0, v1), pkrtz_u(v2, v3));
                    } else {
                        *(float4*)((float*)Cout + (size_t)row*Nc + colb) = make_float4(v0, v1, v2, v3);
                    }
                }
            }
        }

        if (pf) {
            // newest 8 vmem ops are this tile's stores; ensures the 4 DMAs landed
            asm volatile("s_waitcnt vmcnt(8)" ::: "memory");
            __builtin_amdgcn_s_barrier();          // all waves done reading As[cur]
        }
        cur ^= 1;
    }
}

// ---- fused edge-logits + softmax + aggregate + epilogue (packed f16 math) ----------
// 8 waves/block, one node per wave, grid-stride. Lane l: channels l*8..+8 (f16).
// xlr row: [xl 512 | xr 512] f16. Residual h stored ONLY as bf16 (hb); update math fp32.
__global__ __launch_bounds__(512)
void k_aggregate(const unsigned short* __restrict__ xlr,
                 const __half* __restrict__ eprojh,  // [16][512] f16, this layer
                 const int* __restrict__ rowptr, const int* __restrict__ packed,
                 const float* __restrict__ att,      // [4][128], this layer
                 const float* __restrict__ bias,     // [128], this layer
                 unsigned short* __restrict__ hb) {
    __shared__ uint4 eps4[1024];                     // 16 KB
    {
        const uint4* s4 = (const uint4*)eprojh;
        int t = threadIdx.x;
        eps4[t]       = s4[t];
        eps4[t + 512] = s4[t + 512];
    }
    __syncthreads();

    const int wave = threadIdx.x >> 6;
    const int lane = threadIdx.x & 63;
    const int loff = lane*8;                         // ushort index into row
    const h2 k02 = {(_Float16)0.2f, (_Float16)0.2f};

    h2 attf[4];
    {
        float4 a0 = *(const float4*)(att + loff);
        float4 a1 = *(const float4*)(att + loff + 4);
        attf[0] = (h2){(_Float16)a0.x, (_Float16)a0.y};
        attf[1] = (h2){(_Float16)a0.z, (_Float16)a0.w};
        attf[2] = (h2){(_Float16)a1.x, (_Float16)a1.y};
        attf[3] = (h2){(_Float16)a1.z, (_Float16)a1.w};
    }

#define EDGE_PROC(xr_, er_) do {                                            \
        h2 x0 = as_h2(xr_.x), x1 = as_h2(xr_.y);                            \
        h2 x2 = as_h2(xr_.z), x3 = as_h2(xr_.w);                            \
        h2 z0 = x0 + xrf[0] + as_h2(er_.x);                                 \
        h2 z1 = x1 + xrf[1] + as_h2(er_.y);                                 \
        h2 z2 = x2 + xrf[2] + as_h2(er_.z);                                 \
        h2 z3 = x3 + xrf[3] + as_h2(er_.w);                                 \
        h2 lacc = __builtin_elementwise_max(z0, z0*k02) * attf[0];          \
        lacc += __builtin_elementwise_max(z1, z1*k02) * attf[1];            \
        lacc += __builtin_elementwise_max(z2, z2*k02) * attf[2];            \
        lacc += __builtin_elementwise_max(z3, z3*k02) * attf[3];            \
        float pz_ = (float)lacc[0] + (float)lacc[1];                        \
        pz_ += __shfl_xor(pz_, 1);                                          \
        pz_ += __shfl_xor(pz_, 2);                                          \
        pz_ += __shfl_xor(pz_, 4);                                          \
        pz_ += __shfl_xor(pz_, 8);                                          \
        float w_ = __expf(pz_);                                             \
        wsum += w_;                                                         \
        h2 wh = {(_Float16)w_, (_Float16)w_};                               \
        acc0 += wh*x0; acc1 += wh*x1; acc2 += wh*x2; acc3 += wh*x3;         \
    } while (0)

    for (int g = blockIdx.x; g < NN/8; g += gridDim.x) {
        int n = g*8 + wave;

        h2 xrf[4];
        {
            uint4 raw = *(const uint4*)(xlr + (size_t)n*1024 + 512 + loff);
            xrf[0] = as_h2(raw.x); xrf[1] = as_h2(raw.y);
            xrf[2] = as_h2(raw.z); xrf[3] = as_h2(raw.w);
        }

        h2 acc0 = {0,0}, acc1 = {0,0}, acc2 = {0,0}, acc3 = {0,0};
        float wsum = 0.f;
        int beg = rowptr[n], end = rowptr[n+1];
        int p = beg;

        for (; p + 4 <= end; p += 4) {               // 4 edges in flight
            int pk0 = packed[p],   pk1 = packed[p+1];
            int pk2 = packed[p+2], pk3 = packed[p+3];
            uint4 v0 = *(const uint4*)(xlr + (size_t)(pk0 & 0xFFFF)*1024 + loff);
            uint4 v1 = *(const uint4*)(xlr + (size_t)(pk1 & 0xFFFF)*1024 + loff);
            uint4 v2 = *(const uint4*)(xlr + (size_t)(pk2 & 0xFFFF)*1024 + loff);
            uint4 v3 = *(const uint4*)(xlr + (size_t)(pk3 & 0xFFFF)*1024 + loff);
            uint4 e0 = eps4[(pk0 >> 16)*64 + lane];
            uint4 e1 = eps4[(pk1 >> 16)*64 + lane];
            uint4 e2 = eps4[(pk2 >> 16)*64 + lane];
            uint4 e3 = eps4[(pk3 >> 16)*64 + lane];
            EDGE_PROC(v0, e0);
            EDGE_PROC(v1, e1);
            EDGE_PROC(v2, e2);
            EDGE_PROC(v3, e3);
        }
        if (p + 2 <= end) {                          // 2-wide tail
            int pk0 = packed[p], pk1 = packed[p+1];
            uint4 v0 = *(const uint4*)(xlr + (size_t)(pk0 & 0xFFFF)*1024 + loff);
            uint4 v1 = *(const uint4*)(xlr + (size_t)(pk1 & 0xFFFF)*1024 + loff);
            uint4 e0 = eps4[(pk0 >> 16)*64 + lane];
            uint4 e1 = eps4[(pk1 >> 16)*64 + lane];
            EDGE_PROC(v0, e0);
            EDGE_PROC(v1, e1);
            p += 2;
        }
        if (p < end) {                               // 1-wide tail
            int pk0 = packed[p];
            uint4 v0 = *(const uint4*)(xlr + (size_t)(pk0 & 0xFFFF)*1024 + loff);
            uint4 e0 = eps4[(pk0 >> 16)*64 + lane];
            EDGE_PROC(v0, e0);
        }

        float inv = __builtin_amdgcn_rcpf(wsum + 1e-16f);
        float rr[8];
        rr[0] = (float)acc0[0]; rr[1] = (float)acc0[1];
        rr[2] = (float)acc1[0]; rr[3] = (float)acc1[1];
        rr[4] = (float)acc2[0]; rr[5] = (float)acc2[1];
        rr[6] = (float)acc3[0]; rr[7] = (float)acc3[1];
        #pragma unroll
        for (int u = 0; u < 8; ++u) rr[u] *= inv;
        #pragma unroll
        for (int u = 0; u < 8; ++u) rr[u] += __shfl_xor(rr[u], 16);
        #pragma unroll
        for (int u = 0; u < 8; ++u) rr[u] += __shfl_xor(rr[u], 32);

        if (lane < 16) {
            int c = lane*8;
            unsigned short* hbp = hb + (size_t)n*DD + c;
            ushort4 hu0 = *(const ushort4*)hbp;
            ushort4 hu1 = *(const ushort4*)(hbp + 4);
            float4 b0 = *(const float4*)(bias + c);
            float4 b1 = *(const float4*)(bias + c + 4);
            float o[8];
            o[0] = bf2f(hu0.x) + fmaxf(0.f, fmaf(0.25f, rr[0], b0.x));
            o[1] = bf2f(hu0.y) + fmaxf(0.f, fmaf(0.25f, rr[1], b0.y));
            o[2] = bf2f(hu0.z) + fmaxf(0.f, fmaf(0.25f, rr[2], b0.z));
            o[3] = bf2f(hu0.w) + fmaxf(0.f, fmaf(0.25f, rr[3], b0.w));
            o[4] = bf2f(hu1.x) + fmaxf(0.f, fmaf(0.25f, rr[4], b1.x));
            o[5] = bf2f(hu1.y) + fmaxf(0.f, fmaf(0.25f, rr[5], b1.y));
            o[6] = bf2f(hu1.z) + fmaxf(0.f, fmaf(0.25f, rr[6], b1.z));
            o[7] = bf2f(hu1.w) + fmaxf(0.f, fmaf(0.25f, rr[7], b1.w));
            ushort4 u0 = make_ushort4(f2bf(o[0]), f2bf(o[1]), f2bf(o[2]), f2bf(o[3]));
            ushort4 u1 = make_ushort4(f2bf(o[4]), f2bf(o[5]), f2bf(o[6]), f2bf(o[7]));
            *(ushort4*)hbp       = u0;
            *(ushort4*)(hbp + 4) = u1;
        }
    }
#undef EDGE_PROC
}

// ---------------- bond head v2: MFMA, wave = 16 edges ---------------------------------
__global__ __launch_bounds__(256)
void k_bond(const unsigned short* __restrict__ hb,
            const int* __restrict__ srcv, const int* __restrict__ dstv,
            const unsigned short* __restrict__ Wbt, const float* __restrict__ bb,
            float* __restrict__ out) {
    int lane = threadIdx.x & 63;
    int wave = threadIdx.x >> 6;
    int ebase = blockIdx.x*64 + wave*16;     // NE = 200000 = 3125*64 exact
    int l15 = lane & 15, l4 = lane >> 4;
    int e = ebase + l15;
    const unsigned short* hs = hb + (size_t)srcv[e]*DD;
    const unsigned short* hd = hb + (size_t)dstv[e]*DD;

    bf16x8 bfr[8];
    #pragma unroll
    for (int s = 0; s < 8; ++s)
        bfr[s] = *(const bf16x8*)(Wbt + l15*256 + s*32 + l4*8);

    float bbv = bb[l15];
    f32x4 acc = (f32x4){bbv, bbv, bbv, bbv};
    #pragma unroll
    for (int s = 0; s < 4; ++s) {
        bf16x8 af = *(const bf16x8*)(hs + s*32 + l4*8);
        acc = __builtin_amdgcn_mfma_f32_16x16x32_bf16(af, bfr[s], acc, 0, 0, 0);
    }
    #pragma unroll
    for (int s = 0; s < 4; ++s) {
        bf16x8 af = *(const bf16x8*)(hd + s*32 + l4*8);
        acc = __builtin_amdgcn_mfma_f32_16x16x32_bf16(af, bfr[4+s], acc, 0, 0, 0);
    }
    #pragma unroll
    for (int r = 0; r < 4; ++r)
        out[(size_t)(ebase + l4*4 + r)*16 + l15] = acc[r];
}

// ---------------- host ----------------
extern "C" void kernel_launch(void* const* d_in, const int* in_sizes, int n_in,
                              void* d_out, int out_size, void* d_ws, size_t ws_size,
                              hipStream_t stream) {
    const int*   x        = (const int*)d_in[0];
    const int*   edge_idx = (const int*)d_in[1];
    const int*   eattr    = (const int*)d_in[2];
    const float* atom_emb = (const float*)d_in[3];
    const float* bond_emb = (const float*)d_in[4];
    const float* Wl  = (const float*)d_in[5];
    const float* bl  = (const float*)d_in[6];
    const float* Wr  = (const float*)d_in[7];
    const float* br  = (const float*)d_in[8];
    const float* We  = (const float*)d_in[9];
    const float* att = (const float*)d_in[10];
    const float* bias= (const float*)d_in[11];
    const float* Wa  = (const float*)d_in[12];
    const float* ba  = (const float*)d_in[13];
    const float* Wb  = (const float*)d_in[14];
    const float* bb  = (const float*)d_in[15];

    const int* src = edge_idx;
    const int* dst = edge_idx + NE;

    char* p = (char*)d_ws;
    auto alloc = [&](size_t bytes) -> void* {
        void* r = p; p += (bytes + 255) & ~(size_t)255; return r;
    };
    unsigned short* hb     = (unsigned short*)alloc((size_t)NN*DD*2);
    unsigned short* xlr    = (unsigned short*)alloc((size_t)NN*1024*2);
    unsigned short* Wlrt   = (unsigned short*)alloc((size_t)NL*1024*DD*2);
    float*          blr    = (float*)alloc((size_t)NL*1024*4);
    unsigned short* Wat    = (unsigned short*)alloc((size_t)DD*VAv*2);
    unsigned short* Wbt    = (unsigned short*)alloc((size_t)16*256*2);
    __half*         eprojh = (__half*)alloc((size_t)NL*VBv*HC*2);
    int*            deg    = (int*)alloc((size_t)NN*4);
    int*            exc    = (int*)alloc((size_t)NN*4);
    int*            sums   = (int*)alloc(256*4);
    int*            rowptr = (int*)alloc((size_t)(NN+1)*4);
    int*            cnt    = (int*)alloc((size_t)NN*4);
    int*            packed = (int*)alloc((size_t)NE*4);

    float* atom_out = (float*)d_out;                      // [NN,128]
    float* bond_out = atom_out + (size_t)NN*VAv;          // [NE,16]

    hipMemsetAsync(deg, 0, (size_t)NN*4, stream);
    hipMemsetAsync(cnt, 0, (size_t)NN*4, stream);

    k_embed<<<7500, 256, 0, stream>>>(x, atom_emb, hb);
    k_convw<<<(NL*1024*DD + 255)/256, 256, 0, stream>>>(Wl, Wr, bl, br, Wlrt, blr);
    k_convwa<<<(DD*VAv + 255)/256, 256, 0, stream>>>(Wa, Wat);
    k_convwb<<<16, 256, 0, stream>>>(Wb, Wbt);
    k_eproj<<<(NL*VBv*HC + 255)/256, 256, 0, stream>>>(bond_emb, We, eprojh);

    // CSR by dst
    int nchunks = (NN + SCAN_CHUNK - 1) / SCAN_CHUNK;     // 118
    k_deg<<<(NE+255)/256, 256, 0, stream>>>(dst, deg);
    k_scan1<<<nchunks, SCAN_CHUNK, 0, stream>>>(deg, exc, sums);
    k_scan2<<<1, 128, 0, stream>>>(sums, nchunks);
    k_scan3<<<(NN+256)/256, 256, 0, stream>>>(exc, sums, rowptr);
    k_scatter<<<(NE+255)/256, 256, 0, stream>>>(src, dst, eattr, rowptr, cnt, packed);

    const int MTILES = (NN + 127) / 128;                  // 469
    const int GRP8 = (MTILES + 7) / 8;                    // 59 panels (MT=8)
    const int GRP4 = (MTILES + 3) / 4;                    // 118 panels (MT=4, Wa)
    const int SWZ_BLKS = ((GRP8 + 7) / 8) * 64;           // 512 (8 octets x 64)
    for (int l = 0; l < NL; ++l) {
        const float* att_l  = att  + (size_t)l*NH*VAv;
        const float* bias_l = bias + (size_t)l*DD;
        const unsigned short* Wlrt_l = Wlrt + (size_t)l*1024*DD;
        const float* blr_l = blr + (size_t)l*1024;
        const __half* ep_l = eprojh + (size_t)l*VBv*HC;

        k_gemm_mfma<2, 8, true><<<SWZ_BLKS, 512, 0, stream>>>(hb, Wlrt_l, blr_l, xlr, NN, 1024, GRP8);
        k_aggregate<<<2500, 512, 0, stream>>>(xlr, ep_l, rowptr, packed, att_l, bias_l, hb);
    }

    k_gemm_mfma<0, 4, false><<<dim3(VAv/128, GRP4), 512, 0, stream>>>(hb, Wat, ba, atom_out, NN, VAv, GRP4);
    k_bond<<<NE/64, 256, 0, stream>>>(hb, src, dst, Wbt, bb, bond_out);
}